// Round 9
// baseline (346.285 us; speedup 1.0000x reference)
//
#include <hip/hip_runtime.h>

// Problem constants
#define KC   1024        // codebook size
#define DD   64          // code dim
#define NR   65536       // total rows (16*4096)

#define DECAY     0.99f
#define ONEM      0.01f
#define EPSV      1e-5f
#define MARGIN_W  0.05f   // rescore window: ~25x the split-bf16 error bound

// d_out layout (floats), in reference return order:
#define OFF_ZQ    0
#define OFF_LOSS  4194304
#define OFF_IDX   4194305
#define OFF_NCB   4259841
#define OFF_NECS  4325377
#define OFF_NEW   4326401

// Scratch aliases inside d_out (zeroed/filled by prep, consumed later):
//   cluster counts -> OFF_NECS (1024); cluster sums -> OFF_NEW (65536);
//   SSE -> OFF_LOSS (1); ||c||^2 table -> first 1024 floats of OFF_NCB.
// d_ws layout (bytes): [0,131072) cbh bf16, [131072,262144) cbm bf16,
//   [262144,266240) den table (1024 f32).

typedef float  f32x4  __attribute__((ext_vector_type(4)));
typedef short  bf16x8 __attribute__((ext_vector_type(8)));

__device__ __forceinline__ unsigned short b16(float v) {
    union { float f; unsigned u; } x; x.f = v;
    return (unsigned short)((x.u + 0x7fffu + ((x.u >> 16) & 1u)) >> 16);
}
__device__ __forceinline__ float b2f(unsigned short h) {
    union { unsigned u; float f; } x; x.u = (unsigned)h << 16;
    return x.f;
}

// 256 blocks x 256 threads: zero accumulators, ||c||^2 table, cb hi/mid split.
__global__ void vq_prep(const float* __restrict__ cb, float* __restrict__ out,
                        unsigned short* __restrict__ cbh,
                        unsigned short* __restrict__ cbm) {
    const int tid = blockIdx.x * blockDim.x + threadIdx.x;
    if (tid < 65536) {
        out[OFF_NEW + tid] = 0.0f;               // cluster sums
        const float v = cb[tid];
        const unsigned short h = b16(v);
        cbh[tid] = h;
        cbm[tid] = b16(v - b2f(h));
    }
    if (tid < 1024) {
        out[OFF_NECS + tid] = 0.0f;              // cluster counts
        const float4* c = reinterpret_cast<const float4*>(cb + tid * 64);
        float s = 0.f;
        #pragma unroll
        for (int j = 0; j < 16; ++j) {
            const float4 v = c[j];
            s += v.x*v.x + v.y*v.y + v.z*v.z + v.w*v.w;
        }
        out[OFF_NCB + tid] = s;                  // ||c_k||^2 (fp32)
    }
    if (tid == 0) out[OFF_LOSS] = 0.0f;          // SSE accumulator
}

// 512 blocks x 512 threads (8 waves). Block owns 128 rows; wave owns 16 rows
// and sweeps ALL 1024 codes with mfma_f32_16x16x32_bf16, split-bf16 3-pass
// (hh + h*m + m*h; |err| <~ 2e-3). Rows whose top-2 margin < MARGIN_W get an
// exact fp32 rescore by the whole block (rare), so the argmin matches fp32.
// A-frag: row=lane&15, k=8*(lane>>4)+e. B-frag: col=lane&15, same k.
// D (verified m89): col=lane&15, row=(lane>>4)*4+reg.
__global__ __launch_bounds__(512, 4) void vq_main(const float* __restrict__ z,
                                                  const float* __restrict__ cb,
                                                  const float* __restrict__ cc,
                                                  const unsigned short* __restrict__ cbh,
                                                  const unsigned short* __restrict__ cbm,
                                                  float* __restrict__ out) {
    const int t    = threadIdx.x;
    const int lane = t & 63;
    const int wid  = t >> 6;
    const int rowbase = blockIdx.x * 128;

    __shared__ float s_zs[128 * 68];   // z tile fp32, stride 68 (34816 B)
    __shared__ float s_cc[1024];       // ||c||^2 (4096 B)
    __shared__ int   s_final[128];
    __shared__ float s_rd[512];        // rescore dists; aliased as SSE reduce
    __shared__ int   s_ri[512];
    __shared__ int   s_flag[128];
    __shared__ int   s_nflag;

    if (t == 0) s_nflag = 0;
    s_cc[t]       = cc[t];
    s_cc[t + 512] = cc[t + 512];

    // Stage z tile: 128 rows x 16 float4 = 2048 float4s; 4 per thread.
    const float4* zb4 = reinterpret_cast<const float4*>(z) + (size_t)blockIdx.x * 2048;
    #pragma unroll
    for (int j = 0; j < 4; ++j) {
        const int f = t + 512 * j;
        const float4 v = zb4[f];
        *reinterpret_cast<float4*>(&s_zs[(f >> 4) * 68 + (f & 15) * 4]) = v;
    }
    __syncthreads();

    // --- build A fragments (hi/mid) for this wave's 16 rows, K=64 ---
    bf16x8 a0h, a0m, a1h, a1m;
    {
        const int ar = wid * 16 + (lane & 15);   // A row = lane&15
        const int kb = (lane >> 4) * 8;          // k base = 8*(lane>>4)
        #pragma unroll
        for (int e = 0; e < 8; ++e) {
            const float v0 = s_zs[ar * 68 + kb + e];
            const unsigned short h0 = b16(v0);
            a0h[e] = (short)h0;
            a0m[e] = (short)b16(v0 - b2f(h0));
            const float v1 = s_zs[ar * 68 + 32 + kb + e];
            const unsigned short h1 = b16(v1);
            a1h[e] = (short)h1;
            a1m[e] = (short)b16(v1 - b2f(h1));
        }
    }

    // --- sweep all 1024 codes, 16 per step ---
    const int lcol = lane & 15;
    const int bco  = lcol * 8 + (lane >> 4);     // bf16x8 index within code grp
    const bf16x8* cbh8 = reinterpret_cast<const bf16x8*>(cbh);
    const bf16x8* cbm8 = reinterpret_cast<const bf16x8*>(cbm);

    float bd[4], b2v[4]; int bk[4];
    #pragma unroll
    for (int j = 0; j < 4; ++j) { bd[j] = 3.4e38f; b2v[j] = 3.4e38f; bk[j] = 0; }

    for (int c0 = 0; c0 < 1024; c0 += 16) {
        const bf16x8 bh0 = cbh8[c0 * 8 + bco];
        const bf16x8 bh1 = cbh8[c0 * 8 + bco + 4];
        const bf16x8 bm0 = cbm8[c0 * 8 + bco];
        const bf16x8 bm1 = cbm8[c0 * 8 + bco + 4];
        f32x4 p0 = {0.f, 0.f, 0.f, 0.f};
        f32x4 p1 = {0.f, 0.f, 0.f, 0.f};
        p0 = __builtin_amdgcn_mfma_f32_16x16x32_bf16(a0m, bh0, p0, 0, 0, 0);
        p1 = __builtin_amdgcn_mfma_f32_16x16x32_bf16(a1m, bh1, p1, 0, 0, 0);
        p0 = __builtin_amdgcn_mfma_f32_16x16x32_bf16(a0h, bm0, p0, 0, 0, 0);
        p1 = __builtin_amdgcn_mfma_f32_16x16x32_bf16(a1h, bm1, p1, 0, 0, 0);
        p0 = __builtin_amdgcn_mfma_f32_16x16x32_bf16(a0h, bh0, p0, 0, 0, 0);
        p1 = __builtin_amdgcn_mfma_f32_16x16x32_bf16(a1h, bh1, p1, 0, 0, 0);
        const float ccv = s_cc[c0 + lcol];
        #pragma unroll
        for (int j = 0; j < 4; ++j) {
            const float s = fmaf(-2.f, p0[j] + p1[j], ccv);
            if (s < bd[j]) { b2v[j] = bd[j]; bd[j] = s; bk[j] = c0 + lcol; }
            else if (s < b2v[j]) b2v[j] = s;
        }
    }

    // --- cross-lane argmin over the 16 code-columns (exact first-index) ---
    #pragma unroll
    for (int m = 1; m < 16; m <<= 1) {
        #pragma unroll
        for (int j = 0; j < 4; ++j) {
            const float od = __shfl_xor(bd[j],  m);
            const int   oi = __shfl_xor(bk[j],  m);
            const float o2 = __shfl_xor(b2v[j], m);
            const float nb2 = fminf(fmaxf(bd[j], od), fminf(b2v[j], o2));
            if (od < bd[j] || (od == bd[j] && oi < bk[j])) { bd[j] = od; bk[j] = oi; }
            b2v[j] = nb2;
        }
    }
    if ((lane & 15) == 0) {
        #pragma unroll
        for (int j = 0; j < 4; ++j) {
            const int r = wid * 16 + ((lane >> 4) << 2) + j;   // D row mapping
            s_final[r] = bk[j];
            if (b2v[j] - bd[j] < MARGIN_W) {
                const int p = atomicAdd(&s_nflag, 1);
                s_flag[p] = r;
            }
        }
    }
    __syncthreads();

    // --- exact fp32 rescore for margin-flagged rows (rare) ---
    const int nf = s_nflag;
    for (int i = 0; i < nf; ++i) {
        const int r = s_flag[i];
        float bestd = 3.4e38f; int besti = 0;
        #pragma unroll
        for (int h = 0; h < 2; ++h) {
            const int code = t + 512 * h;
            const float4* c4 = reinterpret_cast<const float4*>(cb + (size_t)code * 64);
            float ac[4] = {0.f, 0.f, 0.f, 0.f};
            #pragma unroll
            for (int q = 0; q < 16; ++q) {
                const float4 zq = *reinterpret_cast<const float4*>(&s_zs[r * 68 + q * 4]);
                const float4 cq = c4[q];
                ac[q & 3] = fmaf(zq.x, cq.x, ac[q & 3]);
                ac[q & 3] = fmaf(zq.y, cq.y, ac[q & 3]);
                ac[q & 3] = fmaf(zq.z, cq.z, ac[q & 3]);
                ac[q & 3] = fmaf(zq.w, cq.w, ac[q & 3]);
            }
            const float d = fmaf(-2.f, (ac[0] + ac[1]) + (ac[2] + ac[3]), s_cc[code]);
            if (d < bestd) { bestd = d; besti = code; }   // h=0 first: low idx on tie
        }
        s_rd[t] = bestd; s_ri[t] = besti;
        __syncthreads();
        for (int off = 256; off > 0; off >>= 1) {
            if (t < off) {
                const float d = s_rd[t + off]; const int ii = s_ri[t + off];
                if (d < s_rd[t] || (d == s_rd[t] && ii < s_ri[t])) {
                    s_rd[t] = d; s_ri[t] = ii;
                }
            }
            __syncthreads();
        }
        if (t == 0) s_final[r] = s_ri[0];
        __syncthreads();
    }

    // --- indices + counts ---
    if (t < 128) {
        const int k2 = s_final[t];
        out[OFF_IDX + rowbase + t] = (float)k2;
        atomicAdd(&out[OFF_NECS + k2], 1.0f);
    }

    // --- phase 2: z_q write + commitment SSE + cluster-sum atomics ---
    float sse = 0.f;
    float4*       qb  = reinterpret_cast<float4*>(out + OFF_ZQ) + (size_t)blockIdx.x * 2048;
    const float4* cb4 = reinterpret_cast<const float4*>(cb);
    #pragma unroll
    for (int j = 0; j < 4; ++j) {
        const int f  = t + 512 * j;
        const int r  = f >> 4;
        const int fc = f & 15;
        const int gk = s_final[r];
        const float4 zv = *reinterpret_cast<const float4*>(&s_zs[r * 68 + fc * 4]);
        const float4 cv = cb4[gk * 16 + fc];
        qb[f] = cv;                      // z_q_st == z_q numerically
        const float e0 = zv.x - cv.x, e1 = zv.y - cv.y;
        const float e2 = zv.z - cv.z, e3 = zv.w - cv.w;
        sse += e0 * e0 + e1 * e1 + e2 * e2 + e3 * e3;
        float* sp = out + OFF_NEW + gk * 64 + fc * 4;
        atomicAdd(sp + 0, zv.x);
        atomicAdd(sp + 1, zv.y);
        atomicAdd(sp + 2, zv.z);
        atomicAdd(sp + 3, zv.w);
    }

    float* s_red = s_rd;                 // reuse rescore buffer for SSE reduce
    s_red[t] = sse;
    __syncthreads();
    for (int off = 256; off > 0; off >>= 1) {
        if (t < off) s_red[t] += s_red[t + off];
        __syncthreads();
    }
    if (t == 0) atomicAdd(&out[OFF_LOSS], s_red[0]);
}

// One block, 1024 threads: EMA cluster-size update + n-reduction + den table.
__global__ __launch_bounds__(1024) void vq_final_a(const float* __restrict__ ema_cs,
                                                   float* __restrict__ out,
                                                   float* __restrict__ den) {
    const int k = threadIdx.x;
    const float cnt  = out[OFF_NECS + k];
    const float necs = DECAY * ema_cs[k] + ONEM * cnt;

    __shared__ float s_red[1024];
    s_red[k] = necs;
    __syncthreads();
    for (int off = 512; off > 0; off >>= 1) {
        if (k < off) s_red[k] += s_red[k + off];
        __syncthreads();
    }
    const float n = s_red[0];

    out[OFF_NECS + k] = necs;
    den[k] = (necs + EPSV) / (n + (float)KC * EPSV) * n;
    if (k == 0) out[OFF_LOSS] = 0.25f * out[OFF_LOSS] * (1.f / 4194304.f);
}

// 64 blocks x 1024 threads: EMA w update + codebook normalization.
__global__ __launch_bounds__(1024) void vq_final_b(const float* __restrict__ ema_w,
                                                   const float* __restrict__ den,
                                                   float* __restrict__ out) {
    const int e = blockIdx.x * 1024 + threadIdx.x;      // 0..65535, coalesced
    const float s  = out[OFF_NEW + e];                  // raw cluster sum
    const float ew = DECAY * ema_w[e] + ONEM * s;
    out[OFF_NEW + e] = ew;                              // new_ew
    out[OFF_NCB + e] = ew / den[e >> 6];                // new_codebook
}

extern "C" void kernel_launch(void* const* d_in, const int* in_sizes, int n_in,
                              void* d_out, int out_size, void* d_ws, size_t ws_size,
                              hipStream_t stream) {
    const float* z   = (const float*)d_in[0];
    const float* cb  = (const float*)d_in[1];
    const float* ecs = (const float*)d_in[2];
    const float* ew  = (const float*)d_in[3];
    float* out = (float*)d_out;

    unsigned short* cbh = (unsigned short*)d_ws;
    unsigned short* cbm = (unsigned short*)((char*)d_ws + 131072);
    float*          den = (float*)((char*)d_ws + 262144);

    vq_prep   <<<256, 256, 0, stream>>>(cb, out, cbh, cbm);
    vq_main   <<<512, 512, 0, stream>>>(z, cb, out + OFF_NCB, cbh, cbm, out);
    vq_final_a<<<1,  1024, 0, stream>>>(ecs, out, den);
    vq_final_b<<<64, 1024, 0, stream>>>(ew, den, out);
}

// Round 10
// 271.351 us; speedup vs baseline: 1.2762x; 1.2762x over previous
//
#include <hip/hip_runtime.h>

// Problem constants
#define KC   1024        // codebook size
#define DD   64          // code dim
#define NR   65536       // total rows (16*4096)

#define DECAY     0.99f
#define ONEM      0.01f
#define EPSV      1e-5f
#define MARGIN_W  0.05f   // rescore window: ~25x the split-bf16 error bound

// d_out layout (floats), in reference return order:
#define OFF_ZQ    0
#define OFF_LOSS  4194304
#define OFF_IDX   4194305
#define OFF_NCB   4259841
#define OFF_NECS  4325377
#define OFF_NEW   4326401

// Scratch aliases inside d_out (zeroed/filled by prep, consumed later):
//   cluster counts -> OFF_NECS (1024); cluster sums -> OFF_NEW (65536);
//   SSE -> OFF_LOSS (1); ||c||^2 table -> first 1024 floats of OFF_NCB.
// d_ws layout (bytes): [0,131072) cbh bf16 (fragment-permuted),
//   [131072,262144) cbm bf16 (fragment-permuted), [262144,266240) den (f32).

typedef float  f32x4  __attribute__((ext_vector_type(4)));
typedef short  bf16x8 __attribute__((ext_vector_type(8)));

__device__ __forceinline__ unsigned short b16(float v) {
    union { float f; unsigned u; } x; x.f = v;
    return (unsigned short)((x.u + 0x7fffu + ((x.u >> 16) & 1u)) >> 16);
}
__device__ __forceinline__ float b2f(unsigned short h) {
    union { unsigned u; float f; } x; x.u = (unsigned)h << 16;
    return x.f;
}

// 256 blocks x 256 threads: zero accumulators, ||c||^2 table, and the
// FRAGMENT-PERMUTED hi/mid codebook splits. Permutation: element (code,d)
// with code=16g+col, d=32*kh+8*hi2+e goes to [((g*2+kh)*64 + hi2*16+col)*8+e]
// so a wave's B-fragment load is lane-linear (one 1KB coalesced transaction).
__global__ void vq_prep(const float* __restrict__ cb, float* __restrict__ out,
                        unsigned short* __restrict__ cbh,
                        unsigned short* __restrict__ cbm) {
    const int tid = blockIdx.x * blockDim.x + threadIdx.x;
    if (tid < 65536) {
        out[OFF_NEW + tid] = 0.0f;               // cluster sums
        const int code = tid >> 6, d = tid & 63;
        const int g   = code >> 4, col = code & 15;
        const int kh  = d >> 5, hi2 = (d >> 3) & 3, e = d & 7;
        const int pi  = ((g * 2 + kh) * 64 + hi2 * 16 + col) * 8 + e;
        const float v = cb[tid];
        const unsigned short h = b16(v);
        cbh[pi] = h;
        cbm[pi] = b16(v - b2f(h));
    }
    if (tid < 1024) {
        out[OFF_NECS + tid] = 0.0f;              // cluster counts
        const float4* c = reinterpret_cast<const float4*>(cb + tid * 64);
        float s = 0.f;
        #pragma unroll
        for (int j = 0; j < 16; ++j) {
            const float4 v = c[j];
            s += v.x*v.x + v.y*v.y + v.z*v.z + v.w*v.w;
        }
        out[OFF_NCB + tid] = s;                  // ||c_k||^2 (fp32)
    }
    if (tid == 0) out[OFF_LOSS] = 0.0f;          // SSE accumulator
}

// 512 blocks x 512 threads (8 waves). Block owns 128 rows; wave owns 16 rows
// and sweeps ALL 1024 codes with mfma_f32_16x16x32_bf16, split-bf16 3-pass
// (hh + h*m + m*h; |err| <~ 2e-3). Rows whose top-2 margin < MARGIN_W get an
// exact fp32 rescore by the whole block (rare), so the argmin matches fp32.
// B loads are lane-linear coalesced (prep pre-permuted) + 1-step prefetch.
__global__ __launch_bounds__(512, 4) void vq_main(const float* __restrict__ z,
                                                  const float* __restrict__ cb,
                                                  const float* __restrict__ cc,
                                                  const unsigned short* __restrict__ cbh,
                                                  const unsigned short* __restrict__ cbm,
                                                  float* __restrict__ out) {
    const int t    = threadIdx.x;
    const int lane = t & 63;
    const int wid  = t >> 6;
    const int rowbase = blockIdx.x * 128;

    __shared__ float s_zs[128 * 68];   // z tile fp32, stride 68 (34816 B)
    __shared__ float s_cc[1024];       // ||c||^2 (4096 B)
    __shared__ int   s_final[128];
    __shared__ float s_rd[512];        // rescore dists; aliased as SSE reduce
    __shared__ int   s_ri[512];
    __shared__ int   s_flag[128];
    __shared__ int   s_nflag;

    if (t == 0) s_nflag = 0;
    s_cc[t]       = cc[t];
    s_cc[t + 512] = cc[t + 512];

    // Stage z tile: 128 rows x 16 float4 = 2048 float4s; 4 per thread.
    const float4* zb4 = reinterpret_cast<const float4*>(z) + (size_t)blockIdx.x * 2048;
    #pragma unroll
    for (int j = 0; j < 4; ++j) {
        const int f = t + 512 * j;
        const float4 v = zb4[f];
        *reinterpret_cast<float4*>(&s_zs[(f >> 4) * 68 + (f & 15) * 4]) = v;
    }
    __syncthreads();

    // --- build A fragments (hi/mid) for this wave's 16 rows, K=64 ---
    bf16x8 a0h, a0m, a1h, a1m;
    {
        const int ar = wid * 16 + (lane & 15);   // A row = lane&15
        const int kb = (lane >> 4) * 8;          // k base = 8*(lane>>4)
        #pragma unroll
        for (int e = 0; e < 8; ++e) {
            const float v0 = s_zs[ar * 68 + kb + e];
            const unsigned short h0 = b16(v0);
            a0h[e] = (short)h0;
            a0m[e] = (short)b16(v0 - b2f(h0));
            const float v1 = s_zs[ar * 68 + 32 + kb + e];
            const unsigned short h1 = b16(v1);
            a1h[e] = (short)h1;
            a1m[e] = (short)b16(v1 - b2f(h1));
        }
    }

    // --- sweep all 1024 codes, 16 per step, coalesced + prefetched B ---
    const int lcol = lane & 15;
    const bf16x8* cbh8 = reinterpret_cast<const bf16x8*>(cbh);
    const bf16x8* cbm8 = reinterpret_cast<const bf16x8*>(cbm);

    float bd[4], b2v[4]; int bk[4];
    #pragma unroll
    for (int j = 0; j < 4; ++j) { bd[j] = 3.4e38f; b2v[j] = 3.4e38f; bk[j] = 0; }

    bf16x8 bh0 = cbh8[lane],      bh1 = cbh8[64 + lane];
    bf16x8 bm0 = cbm8[lane],      bm1 = cbm8[64 + lane];
    for (int g = 0; g < 64; ++g) {
        const int nb = ((g + 1) & 63) * 128;     // wrap: last prefetch harmless
        const bf16x8 nh0 = cbh8[nb + lane],      nh1 = cbh8[nb + 64 + lane];
        const bf16x8 nm0 = cbm8[nb + lane],      nm1 = cbm8[nb + 64 + lane];

        f32x4 p0 = {0.f, 0.f, 0.f, 0.f};
        f32x4 p1 = {0.f, 0.f, 0.f, 0.f};
        p0 = __builtin_amdgcn_mfma_f32_16x16x32_bf16(a0m, bh0, p0, 0, 0, 0);
        p1 = __builtin_amdgcn_mfma_f32_16x16x32_bf16(a1m, bh1, p1, 0, 0, 0);
        p0 = __builtin_amdgcn_mfma_f32_16x16x32_bf16(a0h, bm0, p0, 0, 0, 0);
        p1 = __builtin_amdgcn_mfma_f32_16x16x32_bf16(a1h, bm1, p1, 0, 0, 0);
        p0 = __builtin_amdgcn_mfma_f32_16x16x32_bf16(a0h, bh0, p0, 0, 0, 0);
        p1 = __builtin_amdgcn_mfma_f32_16x16x32_bf16(a1h, bh1, p1, 0, 0, 0);

        const float ccv = s_cc[g * 16 + lcol];
        #pragma unroll
        for (int j = 0; j < 4; ++j) {
            const float s = fmaf(-2.f, p0[j] + p1[j], ccv);
            if (s < bd[j]) { b2v[j] = bd[j]; bd[j] = s; bk[j] = g * 16 + lcol; }
            else if (s < b2v[j]) b2v[j] = s;
        }
        bh0 = nh0; bh1 = nh1; bm0 = nm0; bm1 = nm1;
    }

    // --- cross-lane argmin over the 16 code-columns (exact first-index) ---
    #pragma unroll
    for (int m = 1; m < 16; m <<= 1) {
        #pragma unroll
        for (int j = 0; j < 4; ++j) {
            const float od = __shfl_xor(bd[j],  m);
            const int   oi = __shfl_xor(bk[j],  m);
            const float o2 = __shfl_xor(b2v[j], m);
            const float nb2 = fminf(fmaxf(bd[j], od), fminf(b2v[j], o2));
            if (od < bd[j] || (od == bd[j] && oi < bk[j])) { bd[j] = od; bk[j] = oi; }
            b2v[j] = nb2;
        }
    }
    if ((lane & 15) == 0) {
        #pragma unroll
        for (int j = 0; j < 4; ++j) {
            const int r = wid * 16 + ((lane >> 4) << 2) + j;   // D row mapping
            s_final[r] = bk[j];
            if (b2v[j] - bd[j] < MARGIN_W) {
                const int p = atomicAdd(&s_nflag, 1);
                s_flag[p] = r;
            }
        }
    }
    __syncthreads();

    // --- exact fp32 rescore for margin-flagged rows (rare) ---
    const int nf = s_nflag;
    for (int i = 0; i < nf; ++i) {
        const int r = s_flag[i];
        float bestd = 3.4e38f; int besti = 0;
        #pragma unroll
        for (int h = 0; h < 2; ++h) {
            const int code = t + 512 * h;
            const float4* c4 = reinterpret_cast<const float4*>(cb + (size_t)code * 64);
            float ac[4] = {0.f, 0.f, 0.f, 0.f};
            #pragma unroll
            for (int q = 0; q < 16; ++q) {
                const float4 zq = *reinterpret_cast<const float4*>(&s_zs[r * 68 + q * 4]);
                const float4 cq = c4[q];
                ac[q & 3] = fmaf(zq.x, cq.x, ac[q & 3]);
                ac[q & 3] = fmaf(zq.y, cq.y, ac[q & 3]);
                ac[q & 3] = fmaf(zq.z, cq.z, ac[q & 3]);
                ac[q & 3] = fmaf(zq.w, cq.w, ac[q & 3]);
            }
            const float d = fmaf(-2.f, (ac[0] + ac[1]) + (ac[2] + ac[3]), s_cc[code]);
            if (d < bestd) { bestd = d; besti = code; }   // h=0 first: low idx on tie
        }
        s_rd[t] = bestd; s_ri[t] = besti;
        __syncthreads();
        for (int off = 256; off > 0; off >>= 1) {
            if (t < off) {
                const float d = s_rd[t + off]; const int ii = s_ri[t + off];
                if (d < s_rd[t] || (d == s_rd[t] && ii < s_ri[t])) {
                    s_rd[t] = d; s_ri[t] = ii;
                }
            }
            __syncthreads();
        }
        if (t == 0) s_final[r] = s_ri[0];
        __syncthreads();
    }

    // --- indices + counts ---
    if (t < 128) {
        const int k2 = s_final[t];
        out[OFF_IDX + rowbase + t] = (float)k2;
        atomicAdd(&out[OFF_NECS + k2], 1.0f);
    }

    // --- phase 2: z_q write + commitment SSE + cluster-sum atomics ---
    float sse = 0.f;
    float4*       qb  = reinterpret_cast<float4*>(out + OFF_ZQ) + (size_t)blockIdx.x * 2048;
    const float4* cb4 = reinterpret_cast<const float4*>(cb);
    #pragma unroll
    for (int j = 0; j < 4; ++j) {
        const int f  = t + 512 * j;
        const int r  = f >> 4;
        const int fc = f & 15;
        const int gk = s_final[r];
        const float4 zv = *reinterpret_cast<const float4*>(&s_zs[r * 68 + fc * 4]);
        const float4 cv = cb4[gk * 16 + fc];
        qb[f] = cv;                      // z_q_st == z_q numerically
        const float e0 = zv.x - cv.x, e1 = zv.y - cv.y;
        const float e2 = zv.z - cv.z, e3 = zv.w - cv.w;
        sse += e0 * e0 + e1 * e1 + e2 * e2 + e3 * e3;
        float* sp = out + OFF_NEW + gk * 64 + fc * 4;
        atomicAdd(sp + 0, zv.x);
        atomicAdd(sp + 1, zv.y);
        atomicAdd(sp + 2, zv.z);
        atomicAdd(sp + 3, zv.w);
    }

    float* s_red = s_rd;                 // reuse rescore buffer for SSE reduce
    s_red[t] = sse;
    __syncthreads();
    for (int off = 256; off > 0; off >>= 1) {
        if (t < off) s_red[t] += s_red[t + off];
        __syncthreads();
    }
    if (t == 0) atomicAdd(&out[OFF_LOSS], s_red[0]);
}

// One block, 1024 threads: EMA cluster-size update + n-reduction + den table.
__global__ __launch_bounds__(1024) void vq_final_a(const float* __restrict__ ema_cs,
                                                   float* __restrict__ out,
                                                   float* __restrict__ den) {
    const int k = threadIdx.x;
    const float cnt  = out[OFF_NECS + k];
    const float necs = DECAY * ema_cs[k] + ONEM * cnt;

    __shared__ float s_red[1024];
    s_red[k] = necs;
    __syncthreads();
    for (int off = 512; off > 0; off >>= 1) {
        if (k < off) s_red[k] += s_red[k + off];
        __syncthreads();
    }
    const float n = s_red[0];

    out[OFF_NECS + k] = necs;
    den[k] = (necs + EPSV) / (n + (float)KC * EPSV) * n;
    if (k == 0) out[OFF_LOSS] = 0.25f * out[OFF_LOSS] * (1.f / 4194304.f);
}

// 64 blocks x 1024 threads: EMA w update + codebook normalization.
__global__ __launch_bounds__(1024) void vq_final_b(const float* __restrict__ ema_w,
                                                   const float* __restrict__ den,
                                                   float* __restrict__ out) {
    const int e = blockIdx.x * 1024 + threadIdx.x;      // 0..65535, coalesced
    const float s  = out[OFF_NEW + e];                  // raw cluster sum
    const float ew = DECAY * ema_w[e] + ONEM * s;
    out[OFF_NEW + e] = ew;                              // new_ew
    out[OFF_NCB + e] = ew / den[e >> 6];                // new_codebook
}

extern "C" void kernel_launch(void* const* d_in, const int* in_sizes, int n_in,
                              void* d_out, int out_size, void* d_ws, size_t ws_size,
                              hipStream_t stream) {
    const float* z   = (const float*)d_in[0];
    const float* cb  = (const float*)d_in[1];
    const float* ecs = (const float*)d_in[2];
    const float* ew  = (const float*)d_in[3];
    float* out = (float*)d_out;

    unsigned short* cbh = (unsigned short*)d_ws;
    unsigned short* cbm = (unsigned short*)((char*)d_ws + 131072);
    float*          den = (float*)((char*)d_ws + 262144);

    vq_prep   <<<256, 256, 0, stream>>>(cb, out, cbh, cbm);
    vq_main   <<<512, 512, 0, stream>>>(z, cb, out + OFF_NCB, cbh, cbm, out);
    vq_final_a<<<1,  1024, 0, stream>>>(ecs, out, den);
    vq_final_b<<<64, 1024, 0, stream>>>(ew, den, out);
}

// Round 11
// 251.509 us; speedup vs baseline: 1.3768x; 1.0789x over previous
//
#include <hip/hip_runtime.h>

// Problem constants
#define KC   1024        // codebook size
#define DD   64          // code dim
#define NR   65536       // total rows (16*4096)

#define DECAY     0.99f
#define ONEM      0.01f
#define EPSV      1e-5f
#define MARGIN_W  0.05f   // rescore window: ~25x the split-bf16 error bound

// d_out layout (floats), in reference return order:
#define OFF_ZQ    0
#define OFF_LOSS  4194304
#define OFF_IDX   4194305
#define OFF_NCB   4259841
#define OFF_NECS  4325377
#define OFF_NEW   4326401

// Scratch aliases inside d_out:
//   SSE -> OFF_LOSS (zeroed by prep); ||c||^2 table -> first 1024 of OFF_NCB.
//   OFF_NEW / OFF_NECS are now fully WRITTEN by vq_sums (no atomics, no zeroing).
// d_ws layout (bytes): [0,131072) cbh bf16 (fragment-permuted),
//   [131072,262144) cbm bf16 (fragment-permuted), [262144,266240) den (f32).

typedef float  f32x4  __attribute__((ext_vector_type(4)));
typedef short  bf16x8 __attribute__((ext_vector_type(8)));

__device__ __forceinline__ unsigned short b16(float v) {
    union { float f; unsigned u; } x; x.f = v;
    return (unsigned short)((x.u + 0x7fffu + ((x.u >> 16) & 1u)) >> 16);
}
__device__ __forceinline__ float b2f(unsigned short h) {
    union { unsigned u; float f; } x; x.u = (unsigned)h << 16;
    return x.f;
}

// 256 blocks x 256 threads: ||c||^2 table + fragment-permuted hi/mid splits.
__global__ void vq_prep(const float* __restrict__ cb, float* __restrict__ out,
                        unsigned short* __restrict__ cbh,
                        unsigned short* __restrict__ cbm) {
    const int tid = blockIdx.x * blockDim.x + threadIdx.x;
    if (tid < 65536) {
        const int code = tid >> 6, d = tid & 63;
        const int g   = code >> 4, col = code & 15;
        const int kh  = d >> 5, hi2 = (d >> 3) & 3, e = d & 7;
        const int pi  = ((g * 2 + kh) * 64 + hi2 * 16 + col) * 8 + e;
        const float v = cb[tid];
        const unsigned short h = b16(v);
        cbh[pi] = h;
        cbm[pi] = b16(v - b2f(h));
    }
    if (tid < 1024) {
        const float4* c = reinterpret_cast<const float4*>(cb + tid * 64);
        float s = 0.f;
        #pragma unroll
        for (int j = 0; j < 16; ++j) {
            const float4 v = c[j];
            s += v.x*v.x + v.y*v.y + v.z*v.z + v.w*v.w;
        }
        out[OFF_NCB + tid] = s;                  // ||c_k||^2 (fp32)
    }
    if (tid == 0) out[OFF_LOSS] = 0.0f;          // SSE accumulator
}

// 512 blocks x 512 threads (8 waves). Block owns 128 rows; wave owns 16 rows
// and sweeps ALL 1024 codes with mfma_f32_16x16x32_bf16, split-bf16 3-pass
// (hh + h*m + m*h; |err| <~ 2e-3). Rows whose top-2 margin < MARGIN_W get an
// exact fp32 rescore by the whole block (rare), so the argmin matches fp32.
// Phase 2 writes z_q + SSE only -- NO cluster atomics (round-10 finding:
// the 4.19M contended fp32 atomics were the ~270us session-wide floor).
__global__ __launch_bounds__(512, 4) void vq_main(const float* __restrict__ z,
                                                  const float* __restrict__ cb,
                                                  const float* __restrict__ cc,
                                                  const unsigned short* __restrict__ cbh,
                                                  const unsigned short* __restrict__ cbm,
                                                  float* __restrict__ out) {
    const int t    = threadIdx.x;
    const int lane = t & 63;
    const int wid  = t >> 6;
    const int rowbase = blockIdx.x * 128;

    __shared__ float s_zs[128 * 68];   // z tile fp32, stride 68 (34816 B)
    __shared__ float s_cc[1024];       // ||c||^2 (4096 B)
    __shared__ int   s_final[128];
    __shared__ float s_rd[512];        // rescore dists; aliased as SSE reduce
    __shared__ int   s_ri[512];
    __shared__ int   s_flag[128];
    __shared__ int   s_nflag;

    if (t == 0) s_nflag = 0;
    s_cc[t]       = cc[t];
    s_cc[t + 512] = cc[t + 512];

    // Stage z tile: 128 rows x 16 float4 = 2048 float4s; 4 per thread.
    const float4* zb4 = reinterpret_cast<const float4*>(z) + (size_t)blockIdx.x * 2048;
    #pragma unroll
    for (int j = 0; j < 4; ++j) {
        const int f = t + 512 * j;
        const float4 v = zb4[f];
        *reinterpret_cast<float4*>(&s_zs[(f >> 4) * 68 + (f & 15) * 4]) = v;
    }
    __syncthreads();

    // --- build A fragments (hi/mid) for this wave's 16 rows, K=64 ---
    bf16x8 a0h, a0m, a1h, a1m;
    {
        const int ar = wid * 16 + (lane & 15);   // A row = lane&15
        const int kb = (lane >> 4) * 8;          // k base = 8*(lane>>4)
        #pragma unroll
        for (int e = 0; e < 8; ++e) {
            const float v0 = s_zs[ar * 68 + kb + e];
            const unsigned short h0 = b16(v0);
            a0h[e] = (short)h0;
            a0m[e] = (short)b16(v0 - b2f(h0));
            const float v1 = s_zs[ar * 68 + 32 + kb + e];
            const unsigned short h1 = b16(v1);
            a1h[e] = (short)h1;
            a1m[e] = (short)b16(v1 - b2f(h1));
        }
    }

    // --- sweep all 1024 codes, 16 per step, coalesced + prefetched B ---
    const int lcol = lane & 15;
    const bf16x8* cbh8 = reinterpret_cast<const bf16x8*>(cbh);
    const bf16x8* cbm8 = reinterpret_cast<const bf16x8*>(cbm);

    float bd[4], b2v[4]; int bk[4];
    #pragma unroll
    for (int j = 0; j < 4; ++j) { bd[j] = 3.4e38f; b2v[j] = 3.4e38f; bk[j] = 0; }

    bf16x8 bh0 = cbh8[lane],      bh1 = cbh8[64 + lane];
    bf16x8 bm0 = cbm8[lane],      bm1 = cbm8[64 + lane];
    for (int g = 0; g < 64; ++g) {
        const int nb = ((g + 1) & 63) * 128;     // wrap: last prefetch harmless
        const bf16x8 nh0 = cbh8[nb + lane],      nh1 = cbh8[nb + 64 + lane];
        const bf16x8 nm0 = cbm8[nb + lane],      nm1 = cbm8[nb + 64 + lane];

        f32x4 p0 = {0.f, 0.f, 0.f, 0.f};
        f32x4 p1 = {0.f, 0.f, 0.f, 0.f};
        p0 = __builtin_amdgcn_mfma_f32_16x16x32_bf16(a0m, bh0, p0, 0, 0, 0);
        p1 = __builtin_amdgcn_mfma_f32_16x16x32_bf16(a1m, bh1, p1, 0, 0, 0);
        p0 = __builtin_amdgcn_mfma_f32_16x16x32_bf16(a0h, bm0, p0, 0, 0, 0);
        p1 = __builtin_amdgcn_mfma_f32_16x16x32_bf16(a1h, bm1, p1, 0, 0, 0);
        p0 = __builtin_amdgcn_mfma_f32_16x16x32_bf16(a0h, bh0, p0, 0, 0, 0);
        p1 = __builtin_amdgcn_mfma_f32_16x16x32_bf16(a1h, bh1, p1, 0, 0, 0);

        const float ccv = s_cc[g * 16 + lcol];
        #pragma unroll
        for (int j = 0; j < 4; ++j) {
            const float s = fmaf(-2.f, p0[j] + p1[j], ccv);
            if (s < bd[j]) { b2v[j] = bd[j]; bd[j] = s; bk[j] = g * 16 + lcol; }
            else if (s < b2v[j]) b2v[j] = s;
        }
        bh0 = nh0; bh1 = nh1; bm0 = nm0; bm1 = nm1;
    }

    // --- cross-lane argmin over the 16 code-columns (exact first-index) ---
    #pragma unroll
    for (int m = 1; m < 16; m <<= 1) {
        #pragma unroll
        for (int j = 0; j < 4; ++j) {
            const float od = __shfl_xor(bd[j],  m);
            const int   oi = __shfl_xor(bk[j],  m);
            const float o2 = __shfl_xor(b2v[j], m);
            const float nb2 = fminf(fmaxf(bd[j], od), fminf(b2v[j], o2));
            if (od < bd[j] || (od == bd[j] && oi < bk[j])) { bd[j] = od; bk[j] = oi; }
            b2v[j] = nb2;
        }
    }
    if ((lane & 15) == 0) {
        #pragma unroll
        for (int j = 0; j < 4; ++j) {
            const int r = wid * 16 + ((lane >> 4) << 2) + j;   // D row mapping
            s_final[r] = bk[j];
            if (b2v[j] - bd[j] < MARGIN_W) {
                const int p = atomicAdd(&s_nflag, 1);
                s_flag[p] = r;
            }
        }
    }
    __syncthreads();

    // --- exact fp32 rescore for margin-flagged rows (rare) ---
    const int nf = s_nflag;
    for (int i = 0; i < nf; ++i) {
        const int r = s_flag[i];
        float bestd = 3.4e38f; int besti = 0;
        #pragma unroll
        for (int h = 0; h < 2; ++h) {
            const int code = t + 512 * h;
            const float4* c4 = reinterpret_cast<const float4*>(cb + (size_t)code * 64);
            float ac[4] = {0.f, 0.f, 0.f, 0.f};
            #pragma unroll
            for (int q = 0; q < 16; ++q) {
                const float4 zq = *reinterpret_cast<const float4*>(&s_zs[r * 68 + q * 4]);
                const float4 cq = c4[q];
                ac[q & 3] = fmaf(zq.x, cq.x, ac[q & 3]);
                ac[q & 3] = fmaf(zq.y, cq.y, ac[q & 3]);
                ac[q & 3] = fmaf(zq.z, cq.z, ac[q & 3]);
                ac[q & 3] = fmaf(zq.w, cq.w, ac[q & 3]);
            }
            const float d = fmaf(-2.f, (ac[0] + ac[1]) + (ac[2] + ac[3]), s_cc[code]);
            if (d < bestd) { bestd = d; besti = code; }   // h=0 first: low idx on tie
        }
        s_rd[t] = bestd; s_ri[t] = besti;
        __syncthreads();
        for (int off = 256; off > 0; off >>= 1) {
            if (t < off) {
                const float d = s_rd[t + off]; const int ii = s_ri[t + off];
                if (d < s_rd[t] || (d == s_rd[t] && ii < s_ri[t])) {
                    s_rd[t] = d; s_ri[t] = ii;
                }
            }
            __syncthreads();
        }
        if (t == 0) s_final[r] = s_ri[0];
        __syncthreads();
    }

    // --- indices ---
    if (t < 128) {
        out[OFF_IDX + rowbase + t] = (float)s_final[t];
    }

    // --- phase 2: z_q write + commitment SSE (no cluster atomics) ---
    float sse = 0.f;
    float4*       qb  = reinterpret_cast<float4*>(out + OFF_ZQ) + (size_t)blockIdx.x * 2048;
    const float4* cb4 = reinterpret_cast<const float4*>(cb);
    #pragma unroll
    for (int j = 0; j < 4; ++j) {
        const int f  = t + 512 * j;
        const int r  = f >> 4;
        const int fc = f & 15;
        const int gk = s_final[r];
        const float4 zv = *reinterpret_cast<const float4*>(&s_zs[r * 68 + fc * 4]);
        const float4 cv = cb4[gk * 16 + fc];
        qb[f] = cv;                      // z_q_st == z_q numerically
        const float e0 = zv.x - cv.x, e1 = zv.y - cv.y;
        const float e2 = zv.z - cv.z, e3 = zv.w - cv.w;
        sse += e0 * e0 + e1 * e1 + e2 * e2 + e3 * e3;
    }

    float* s_red = s_rd;                 // reuse rescore buffer for SSE reduce
    s_red[t] = sse;
    __syncthreads();
    for (int off = 256; off > 0; off >>= 1) {
        if (t < off) s_red[t] += s_red[t + off];
        __syncthreads();
    }
    if (t == 0) atomicAdd(&out[OFF_LOSS], s_red[0]);
}

// 512 blocks x 256 threads (4 waves). Block owns codes {2b, 2b+1}; wave w
// scans row stripe [w*16384, (w+1)*16384). Coalesced idx loads (2-deep),
// __ballot match, full-wave coalesced 256B gather per matched row (lane=dim).
// Direct stores of cluster sums + counts: ZERO global atomics, deterministic
// ascending-row summation order.
__global__ __launch_bounds__(256) void vq_sums(const float* __restrict__ z,
                                               float* __restrict__ out) {
    const int t    = threadIdx.x;
    const int lane = t & 63;
    const int w    = t >> 6;
    const int k0   = blockIdx.x * 2;
    const int k1   = k0 + 1;
    const int base = w * 16384;

    float acc0 = 0.f, acc1 = 0.f;
    int   cnt0 = 0,   cnt1 = 0;

    for (int r0 = 0; r0 < 16384; r0 += 128) {
        const int ia = (int)out[OFF_IDX + base + r0 + lane];        // rows r0..+63
        const int ib = (int)out[OFF_IDX + base + r0 + 64 + lane];   // rows +64..+127
        cnt0 += (ia == k0) + (ib == k0);
        cnt1 += (ia == k1) + (ib == k1);
        unsigned long long m;
        m = __ballot(ia == k0);
        while (m) { const int j = __ffsll((long long)m) - 1; m &= m - 1;
                    acc0 += z[(size_t)(base + r0 + j) * 64 + lane]; }
        m = __ballot(ia == k1);
        while (m) { const int j = __ffsll((long long)m) - 1; m &= m - 1;
                    acc1 += z[(size_t)(base + r0 + j) * 64 + lane]; }
        m = __ballot(ib == k0);
        while (m) { const int j = __ffsll((long long)m) - 1; m &= m - 1;
                    acc0 += z[(size_t)(base + r0 + 64 + j) * 64 + lane]; }
        m = __ballot(ib == k1);
        while (m) { const int j = __ffsll((long long)m) - 1; m &= m - 1;
                    acc1 += z[(size_t)(base + r0 + 64 + j) * 64 + lane]; }
    }

    // cross-lane count reduce
    #pragma unroll
    for (int m2 = 32; m2 >= 1; m2 >>= 1) {
        cnt0 += __shfl_xor(cnt0, m2);
        cnt1 += __shfl_xor(cnt1, m2);
    }

    __shared__ float s_a[4][64];
    __shared__ int   s_c[4][2];
    if (lane == 0) { s_c[w][0] = cnt0; s_c[w][1] = cnt1; }
    s_a[w][lane] = acc0;
    __syncthreads();
    if (w == 0) {
        const float s = ((s_a[0][lane] + s_a[1][lane]) + s_a[2][lane]) + s_a[3][lane];
        out[OFF_NEW + k0 * 64 + lane] = s;
        if (lane == 0)
            out[OFF_NECS + k0] = (float)(s_c[0][0] + s_c[1][0] + s_c[2][0] + s_c[3][0]);
    }
    __syncthreads();
    s_a[w][lane] = acc1;
    __syncthreads();
    if (w == 0) {
        const float s = ((s_a[0][lane] + s_a[1][lane]) + s_a[2][lane]) + s_a[3][lane];
        out[OFF_NEW + k1 * 64 + lane] = s;
        if (lane == 0)
            out[OFF_NECS + k1] = (float)(s_c[0][1] + s_c[1][1] + s_c[2][1] + s_c[3][1]);
    }
}

// One block, 1024 threads: EMA cluster-size update + n-reduction + den table.
__global__ __launch_bounds__(1024) void vq_final_a(const float* __restrict__ ema_cs,
                                                   float* __restrict__ out,
                                                   float* __restrict__ den) {
    const int k = threadIdx.x;
    const float cnt  = out[OFF_NECS + k];
    const float necs = DECAY * ema_cs[k] + ONEM * cnt;

    __shared__ float s_red[1024];
    s_red[k] = necs;
    __syncthreads();
    for (int off = 512; off > 0; off >>= 1) {
        if (k < off) s_red[k] += s_red[k + off];
        __syncthreads();
    }
    const float n = s_red[0];

    out[OFF_NECS + k] = necs;
    den[k] = (necs + EPSV) / (n + (float)KC * EPSV) * n;
    if (k == 0) out[OFF_LOSS] = 0.25f * out[OFF_LOSS] * (1.f / 4194304.f);
}

// 64 blocks x 1024 threads: EMA w update + codebook normalization.
__global__ __launch_bounds__(1024) void vq_final_b(const float* __restrict__ ema_w,
                                                   const float* __restrict__ den,
                                                   float* __restrict__ out) {
    const int e = blockIdx.x * 1024 + threadIdx.x;      // 0..65535, coalesced
    const float s  = out[OFF_NEW + e];                  // raw cluster sum
    const float ew = DECAY * ema_w[e] + ONEM * s;
    out[OFF_NEW + e] = ew;                              // new_ew
    out[OFF_NCB + e] = ew / den[e >> 6];                // new_codebook
}

extern "C" void kernel_launch(void* const* d_in, const int* in_sizes, int n_in,
                              void* d_out, int out_size, void* d_ws, size_t ws_size,
                              hipStream_t stream) {
    const float* z   = (const float*)d_in[0];
    const float* cb  = (const float*)d_in[1];
    const float* ecs = (const float*)d_in[2];
    const float* ew  = (const float*)d_in[3];
    float* out = (float*)d_out;

    unsigned short* cbh = (unsigned short*)d_ws;
    unsigned short* cbm = (unsigned short*)((char*)d_ws + 131072);
    float*          den = (float*)((char*)d_ws + 262144);

    vq_prep   <<<256, 256, 0, stream>>>(cb, out, cbh, cbm);
    vq_main   <<<512, 512, 0, stream>>>(z, cb, out + OFF_NCB, cbh, cbm, out);
    vq_sums   <<<512, 256, 0, stream>>>(z, out);
    vq_final_a<<<1,  1024, 0, stream>>>(ecs, out, den);
    vq_final_b<<<64, 1024, 0, stream>>>(ew, den, out);
}

// Round 12
// 219.251 us; speedup vs baseline: 1.5794x; 1.1471x over previous
//
#include <hip/hip_runtime.h>

// Problem constants
#define KC   1024        // codebook size
#define DD   64          // code dim
#define NR   65536       // total rows (16*4096)

#define DECAY     0.99f
#define ONEM      0.01f
#define EPSV      1e-5f
#define MARGIN_W  0.05f   // rescore window: ~25x the split-bf16 error bound

// d_out layout (floats), in reference return order:
#define OFF_ZQ    0
#define OFF_LOSS  4194304
#define OFF_IDX   4194305
#define OFF_NCB   4259841
#define OFF_NECS  4325377
#define OFF_NEW   4326401

// Scratch aliases inside d_out:
//   SSE -> OFF_LOSS (zeroed by prep); ||c||^2 table -> first 1024 of OFF_NCB.
//   OFF_NEW raw sums fully WRITTEN by vq_sums (no atomics, no zeroing).
// d_ws layout (bytes): [0,131072) cbh bf16 (fragment-permuted),
//   [131072,262144) cbm bf16 (fragment-permuted), [262144,266240) cnt (1024 f32).

typedef float  f32x4  __attribute__((ext_vector_type(4)));
typedef short  bf16x8 __attribute__((ext_vector_type(8)));

__device__ __forceinline__ unsigned short b16(float v) {
    union { float f; unsigned u; } x; x.f = v;
    return (unsigned short)((x.u + 0x7fffu + ((x.u >> 16) & 1u)) >> 16);
}
__device__ __forceinline__ float b2f(unsigned short h) {
    union { unsigned u; float f; } x; x.u = (unsigned)h << 16;
    return x.f;
}

// 256 blocks x 256 threads: ||c||^2 table + fragment-permuted hi/mid splits.
__global__ void vq_prep(const float* __restrict__ cb, float* __restrict__ out,
                        unsigned short* __restrict__ cbh,
                        unsigned short* __restrict__ cbm) {
    const int tid = blockIdx.x * blockDim.x + threadIdx.x;
    if (tid < 65536) {
        const int code = tid >> 6, d = tid & 63;
        const int g   = code >> 4, col = code & 15;
        const int kh  = d >> 5, hi2 = (d >> 3) & 3, e = d & 7;
        const int pi  = ((g * 2 + kh) * 64 + hi2 * 16 + col) * 8 + e;
        const float v = cb[tid];
        const unsigned short h = b16(v);
        cbh[pi] = h;
        cbm[pi] = b16(v - b2f(h));
    }
    if (tid < 1024) {
        const float4* c = reinterpret_cast<const float4*>(cb + tid * 64);
        float s = 0.f;
        #pragma unroll
        for (int j = 0; j < 16; ++j) {
            const float4 v = c[j];
            s += v.x*v.x + v.y*v.y + v.z*v.z + v.w*v.w;
        }
        out[OFF_NCB + tid] = s;                  // ||c_k||^2 (fp32)
    }
    if (tid == 0) out[OFF_LOSS] = 0.0f;          // SSE accumulator
}

// 512 blocks x 512 threads (8 waves). Block owns 128 rows; wave owns 16 rows
// and sweeps ALL 1024 codes with mfma_f32_16x16x32_bf16, split-bf16 3-pass
// (hh + h*m + m*h; |err| <~ 2e-3). Margin-flagged rows get exact fp32 rescore.
// launch_bounds(512,2): round-11 finding -- (512,4) gave the MFMA kernel a
// 64-reg arch-VGPR budget (128 split VGPR/AGPR) and the ~90-reg loop spilled
// ~60MB/dispatch of scratch (WRITE_SIZE 77MB vs 17MB real outputs).
__global__ __launch_bounds__(512, 2) void vq_main(const float* __restrict__ z,
                                                  const float* __restrict__ cb,
                                                  const float* __restrict__ cc,
                                                  const unsigned short* __restrict__ cbh,
                                                  const unsigned short* __restrict__ cbm,
                                                  float* __restrict__ out) {
    const int t    = threadIdx.x;
    const int lane = t & 63;
    const int wid  = t >> 6;
    const int rowbase = blockIdx.x * 128;

    __shared__ float s_zs[128 * 68];   // z tile fp32, stride 68 (34816 B)
    __shared__ float s_cc[1024];       // ||c||^2 (4096 B)
    __shared__ int   s_final[128];
    __shared__ float s_rd[512];        // rescore dists; aliased as SSE reduce
    __shared__ int   s_ri[512];
    __shared__ int   s_flag[128];
    __shared__ int   s_nflag;

    if (t == 0) s_nflag = 0;
    s_cc[t]       = cc[t];
    s_cc[t + 512] = cc[t + 512];

    // Stage z tile: 128 rows x 16 float4 = 2048 float4s; 4 per thread.
    const float4* zb4 = reinterpret_cast<const float4*>(z) + (size_t)blockIdx.x * 2048;
    #pragma unroll
    for (int j = 0; j < 4; ++j) {
        const int f = t + 512 * j;
        const float4 v = zb4[f];
        *reinterpret_cast<float4*>(&s_zs[(f >> 4) * 68 + (f & 15) * 4]) = v;
    }
    __syncthreads();

    // --- build A fragments (hi/mid) for this wave's 16 rows, K=64 ---
    bf16x8 a0h, a0m, a1h, a1m;
    {
        const int ar = wid * 16 + (lane & 15);   // A row = lane&15
        const int kb = (lane >> 4) * 8;          // k base = 8*(lane>>4)
        #pragma unroll
        for (int e = 0; e < 8; ++e) {
            const float v0 = s_zs[ar * 68 + kb + e];
            const unsigned short h0 = b16(v0);
            a0h[e] = (short)h0;
            a0m[e] = (short)b16(v0 - b2f(h0));
            const float v1 = s_zs[ar * 68 + 32 + kb + e];
            const unsigned short h1 = b16(v1);
            a1h[e] = (short)h1;
            a1m[e] = (short)b16(v1 - b2f(h1));
        }
    }

    // --- sweep all 1024 codes, 16 per step, coalesced + prefetched B ---
    const int lcol = lane & 15;
    const bf16x8* cbh8 = reinterpret_cast<const bf16x8*>(cbh);
    const bf16x8* cbm8 = reinterpret_cast<const bf16x8*>(cbm);

    float bd[4], b2v[4]; int bk[4];
    #pragma unroll
    for (int j = 0; j < 4; ++j) { bd[j] = 3.4e38f; b2v[j] = 3.4e38f; bk[j] = 0; }

    bf16x8 bh0 = cbh8[lane],      bh1 = cbh8[64 + lane];
    bf16x8 bm0 = cbm8[lane],      bm1 = cbm8[64 + lane];
    for (int g = 0; g < 64; ++g) {
        const int nb = ((g + 1) & 63) * 128;     // wrap: last prefetch harmless
        const bf16x8 nh0 = cbh8[nb + lane],      nh1 = cbh8[nb + 64 + lane];
        const bf16x8 nm0 = cbm8[nb + lane],      nm1 = cbm8[nb + 64 + lane];

        f32x4 p0 = {0.f, 0.f, 0.f, 0.f};
        f32x4 p1 = {0.f, 0.f, 0.f, 0.f};
        p0 = __builtin_amdgcn_mfma_f32_16x16x32_bf16(a0m, bh0, p0, 0, 0, 0);
        p1 = __builtin_amdgcn_mfma_f32_16x16x32_bf16(a1m, bh1, p1, 0, 0, 0);
        p0 = __builtin_amdgcn_mfma_f32_16x16x32_bf16(a0h, bm0, p0, 0, 0, 0);
        p1 = __builtin_amdgcn_mfma_f32_16x16x32_bf16(a1h, bm1, p1, 0, 0, 0);
        p0 = __builtin_amdgcn_mfma_f32_16x16x32_bf16(a0h, bh0, p0, 0, 0, 0);
        p1 = __builtin_amdgcn_mfma_f32_16x16x32_bf16(a1h, bh1, p1, 0, 0, 0);

        const float ccv = s_cc[g * 16 + lcol];
        #pragma unroll
        for (int j = 0; j < 4; ++j) {
            const float s = fmaf(-2.f, p0[j] + p1[j], ccv);
            if (s < bd[j]) { b2v[j] = bd[j]; bd[j] = s; bk[j] = g * 16 + lcol; }
            else if (s < b2v[j]) b2v[j] = s;
        }
        bh0 = nh0; bh1 = nh1; bm0 = nm0; bm1 = nm1;
    }

    // --- cross-lane argmin over the 16 code-columns (exact first-index) ---
    #pragma unroll
    for (int m = 1; m < 16; m <<= 1) {
        #pragma unroll
        for (int j = 0; j < 4; ++j) {
            const float od = __shfl_xor(bd[j],  m);
            const int   oi = __shfl_xor(bk[j],  m);
            const float o2 = __shfl_xor(b2v[j], m);
            const float nb2 = fminf(fmaxf(bd[j], od), fminf(b2v[j], o2));
            if (od < bd[j] || (od == bd[j] && oi < bk[j])) { bd[j] = od; bk[j] = oi; }
            b2v[j] = nb2;
        }
    }
    if ((lane & 15) == 0) {
        #pragma unroll
        for (int j = 0; j < 4; ++j) {
            const int r = wid * 16 + ((lane >> 4) << 2) + j;   // D row mapping
            s_final[r] = bk[j];
            if (b2v[j] - bd[j] < MARGIN_W) {
                const int p = atomicAdd(&s_nflag, 1);
                s_flag[p] = r;
            }
        }
    }
    __syncthreads();

    // --- exact fp32 rescore for margin-flagged rows (rare) ---
    const int nf = s_nflag;
    for (int i = 0; i < nf; ++i) {
        const int r = s_flag[i];
        float bestd = 3.4e38f; int besti = 0;
        #pragma unroll
        for (int h = 0; h < 2; ++h) {
            const int code = t + 512 * h;
            const float4* c4 = reinterpret_cast<const float4*>(cb + (size_t)code * 64);
            float ac[4] = {0.f, 0.f, 0.f, 0.f};
            #pragma unroll
            for (int q = 0; q < 16; ++q) {
                const float4 zq = *reinterpret_cast<const float4*>(&s_zs[r * 68 + q * 4]);
                const float4 cq = c4[q];
                ac[q & 3] = fmaf(zq.x, cq.x, ac[q & 3]);
                ac[q & 3] = fmaf(zq.y, cq.y, ac[q & 3]);
                ac[q & 3] = fmaf(zq.z, cq.z, ac[q & 3]);
                ac[q & 3] = fmaf(zq.w, cq.w, ac[q & 3]);
            }
            const float d = fmaf(-2.f, (ac[0] + ac[1]) + (ac[2] + ac[3]), s_cc[code]);
            if (d < bestd) { bestd = d; besti = code; }   // h=0 first: low idx on tie
        }
        s_rd[t] = bestd; s_ri[t] = besti;
        __syncthreads();
        for (int off = 256; off > 0; off >>= 1) {
            if (t < off) {
                const float d = s_rd[t + off]; const int ii = s_ri[t + off];
                if (d < s_rd[t] || (d == s_rd[t] && ii < s_ri[t])) {
                    s_rd[t] = d; s_ri[t] = ii;
                }
            }
            __syncthreads();
        }
        if (t == 0) s_final[r] = s_ri[0];
        __syncthreads();
    }

    // --- indices ---
    if (t < 128) {
        out[OFF_IDX + rowbase + t] = (float)s_final[t];
    }

    // --- phase 2: z_q write + commitment SSE (no cluster atomics) ---
    float sse = 0.f;
    float4*       qb  = reinterpret_cast<float4*>(out + OFF_ZQ) + (size_t)blockIdx.x * 2048;
    const float4* cb4 = reinterpret_cast<const float4*>(cb);
    #pragma unroll
    for (int j = 0; j < 4; ++j) {
        const int f  = t + 512 * j;
        const int r  = f >> 4;
        const int fc = f & 15;
        const int gk = s_final[r];
        const float4 zv = *reinterpret_cast<const float4*>(&s_zs[r * 68 + fc * 4]);
        const float4 cv = cb4[gk * 16 + fc];
        qb[f] = cv;                      // z_q_st == z_q numerically
        const float e0 = zv.x - cv.x, e1 = zv.y - cv.y;
        const float e2 = zv.z - cv.z, e3 = zv.w - cv.w;
        sse += e0 * e0 + e1 * e1 + e2 * e2 + e3 * e3;
    }

    float* s_red = s_rd;                 // reuse rescore buffer for SSE reduce
    s_red[t] = sse;
    __syncthreads();
    for (int off = 256; off > 0; off >>= 1) {
        if (t < off) s_red[t] += s_red[t + off];
        __syncthreads();
    }
    if (t == 0) atomicAdd(&out[OFF_LOSS], s_red[0]);
}

// 512 blocks x 256 threads (4 waves). Block owns codes {2b, 2b+1}; wave w
// scans row stripe [w*16384, (w+1)*16384). Coalesced idx loads (2-deep),
// __ballot match, full-wave coalesced 256B gather per matched row (lane=dim).
// Sums -> OFF_NEW; counts -> d_ws cnt buffer (so vq_final can read counts
// without racing the OFF_NECS output). ZERO global atomics, deterministic
// ascending-row summation order.
__global__ __launch_bounds__(256) void vq_sums(const float* __restrict__ z,
                                               float* __restrict__ out,
                                               float* __restrict__ cnt) {
    const int t    = threadIdx.x;
    const int lane = t & 63;
    const int w    = t >> 6;
    const int k0   = blockIdx.x * 2;
    const int k1   = k0 + 1;
    const int base = w * 16384;

    float acc0 = 0.f, acc1 = 0.f;
    int   cnt0 = 0,   cnt1 = 0;

    for (int r0 = 0; r0 < 16384; r0 += 128) {
        const int ia = (int)out[OFF_IDX + base + r0 + lane];        // rows r0..+63
        const int ib = (int)out[OFF_IDX + base + r0 + 64 + lane];   // rows +64..+127
        cnt0 += (ia == k0) + (ib == k0);
        cnt1 += (ia == k1) + (ib == k1);
        unsigned long long m;
        m = __ballot(ia == k0);
        while (m) { const int j = __ffsll((long long)m) - 1; m &= m - 1;
                    acc0 += z[(size_t)(base + r0 + j) * 64 + lane]; }
        m = __ballot(ia == k1);
        while (m) { const int j = __ffsll((long long)m) - 1; m &= m - 1;
                    acc1 += z[(size_t)(base + r0 + j) * 64 + lane]; }
        m = __ballot(ib == k0);
        while (m) { const int j = __ffsll((long long)m) - 1; m &= m - 1;
                    acc0 += z[(size_t)(base + r0 + 64 + j) * 64 + lane]; }
        m = __ballot(ib == k1);
        while (m) { const int j = __ffsll((long long)m) - 1; m &= m - 1;
                    acc1 += z[(size_t)(base + r0 + 64 + j) * 64 + lane]; }
    }

    // cross-lane count reduce
    #pragma unroll
    for (int m2 = 32; m2 >= 1; m2 >>= 1) {
        cnt0 += __shfl_xor(cnt0, m2);
        cnt1 += __shfl_xor(cnt1, m2);
    }

    __shared__ float s_a[4][64];
    __shared__ int   s_c[4][2];
    if (lane == 0) { s_c[w][0] = cnt0; s_c[w][1] = cnt1; }
    s_a[w][lane] = acc0;
    __syncthreads();
    if (w == 0) {
        const float s = ((s_a[0][lane] + s_a[1][lane]) + s_a[2][lane]) + s_a[3][lane];
        out[OFF_NEW + k0 * 64 + lane] = s;
        if (lane == 0)
            cnt[k0] = (float)(s_c[0][0] + s_c[1][0] + s_c[2][0] + s_c[3][0]);
    }
    __syncthreads();
    s_a[w][lane] = acc1;
    __syncthreads();
    if (w == 0) {
        const float s = ((s_a[0][lane] + s_a[1][lane]) + s_a[2][lane]) + s_a[3][lane];
        out[OFF_NEW + k1 * 64 + lane] = s;
        if (lane == 0)
            cnt[k1] = (float)(s_c[0][1] + s_c[1][1] + s_c[2][1] + s_c[3][1]);
    }
}

// 64 blocks x 1024 threads: merged finalize. Every block redundantly computes
// necs + n + den for all 1024 codes (4KB of reads, trivial); block b writes
// its 16-code slice of new_ecs and its 1024-element slice of new_ew/new_cb.
// No cross-block races: counts come from ws, OFF_NECS written only by owner.
__global__ __launch_bounds__(1024) void vq_final(const float* __restrict__ ema_cs,
                                                 const float* __restrict__ ema_w,
                                                 const float* __restrict__ cnt,
                                                 float* __restrict__ out) {
    const int k = threadIdx.x;           // code 0..1023
    const int b = blockIdx.x;
    const float necs = DECAY * ema_cs[k] + ONEM * cnt[k];

    __shared__ float s_red[1024];
    __shared__ float s_den[1024];
    s_red[k] = necs;
    __syncthreads();
    for (int off = 512; off > 0; off >>= 1) {
        if (k < off) s_red[k] += s_red[k + off];
        __syncthreads();
    }
    const float n = s_red[0];
    s_den[k] = (necs + EPSV) / (n + (float)KC * EPSV) * n;
    if (k >= b * 16 && k < (b + 1) * 16) out[OFF_NECS + k] = necs;
    __syncthreads();

    const int e = b * 1024 + k;          // this block's slice, coalesced
    const float s  = out[OFF_NEW + e];   // raw cluster sum
    const float ew = DECAY * ema_w[e] + ONEM * s;
    out[OFF_NEW + e] = ew;               // new_ew
    out[OFF_NCB + e] = ew / s_den[e >> 6];  // new_codebook
    if (b == 0 && k == 0) out[OFF_LOSS] = 0.25f * out[OFF_LOSS] * (1.f / 4194304.f);
}

extern "C" void kernel_launch(void* const* d_in, const int* in_sizes, int n_in,
                              void* d_out, int out_size, void* d_ws, size_t ws_size,
                              hipStream_t stream) {
    const float* z   = (const float*)d_in[0];
    const float* cb  = (const float*)d_in[1];
    const float* ecs = (const float*)d_in[2];
    const float* ew  = (const float*)d_in[3];
    float* out = (float*)d_out;

    unsigned short* cbh = (unsigned short*)d_ws;
    unsigned short* cbm = (unsigned short*)((char*)d_ws + 131072);
    float*          cnt = (float*)((char*)d_ws + 262144);

    vq_prep <<<256, 256, 0, stream>>>(cb, out, cbh, cbm);
    vq_main <<<512, 512, 0, stream>>>(z, cb, out + OFF_NCB, cbh, cbm, out);
    vq_sums <<<512, 256, 0, stream>>>(z, out, cnt);
    vq_final<<<64, 1024, 0, stream>>>(ecs, ew, cnt, out);
}

// Round 13
// 166.947 us; speedup vs baseline: 2.0742x; 1.3133x over previous
//
#include <hip/hip_runtime.h>

// Problem constants
#define KC   1024        // codebook size
#define DD   64          // code dim
#define NR   65536       // total rows (16*4096)

#define DECAY     0.99f
#define ONEM      0.01f
#define EPSV      1e-5f
#define MARGIN_W  0.05f   // rescore window: ~25x the split-bf16 error bound

// d_out layout (floats), in reference return order:
#define OFF_ZQ    0
#define OFF_LOSS  4194304
#define OFF_IDX   4194305
#define OFF_NCB   4259841
#define OFF_NECS  4325377
#define OFF_NEW   4326401

// Scratch aliases inside d_out:
//   SSE -> OFF_LOSS (zeroed by prep); ||c||^2 table -> first 1024 of OFF_NCB.
//   OFF_NEW raw sums fully WRITTEN by vq_sums (no atomics, no zeroing).
// d_ws layout (bytes): [0,131072) cbh bf16 (fragment-permuted),
//   [131072,262144) cbm bf16 (fragment-permuted), [262144,266240) cnt (1024 f32).

typedef float  f32x4  __attribute__((ext_vector_type(4)));
typedef short  bf16x8 __attribute__((ext_vector_type(8)));

__device__ __forceinline__ unsigned short b16(float v) {
    union { float f; unsigned u; } x; x.f = v;
    return (unsigned short)((x.u + 0x7fffu + ((x.u >> 16) & 1u)) >> 16);
}
__device__ __forceinline__ float b2f(unsigned short h) {
    union { unsigned u; float f; } x; x.u = (unsigned)h << 16;
    return x.f;
}

// 256 blocks x 256 threads: ||c||^2 table + fragment-permuted hi/mid splits.
__global__ void vq_prep(const float* __restrict__ cb, float* __restrict__ out,
                        unsigned short* __restrict__ cbh,
                        unsigned short* __restrict__ cbm) {
    const int tid = blockIdx.x * blockDim.x + threadIdx.x;
    if (tid < 65536) {
        const int code = tid >> 6, d = tid & 63;
        const int g   = code >> 4, col = code & 15;
        const int kh  = d >> 5, hi2 = (d >> 3) & 3, e = d & 7;
        const int pi  = ((g * 2 + kh) * 64 + hi2 * 16 + col) * 8 + e;
        const float v = cb[tid];
        const unsigned short h = b16(v);
        cbh[pi] = h;
        cbm[pi] = b16(v - b2f(h));
    }
    if (tid < 1024) {
        const float4* c = reinterpret_cast<const float4*>(cb + tid * 64);
        float s = 0.f;
        #pragma unroll
        for (int j = 0; j < 16; ++j) {
            const float4 v = c[j];
            s += v.x*v.x + v.y*v.y + v.z*v.z + v.w*v.w;
        }
        out[OFF_NCB + tid] = s;                  // ||c_k||^2 (fp32)
    }
    if (tid == 0) out[OFF_LOSS] = 0.0f;          // SSE accumulator
}

// 512 blocks x 512 threads (8 waves). Block owns 128 rows; wave owns 16 rows
// and sweeps ALL 1024 codes with mfma_f32_16x16x32_bf16, split-bf16 3-pass
// (hh + h*m + m*h; |err| <~ 2e-3). Margin-flagged rows get exact fp32 rescore.
// launch_bounds(512,2): round-11 finding -- (512,4) gave the MFMA kernel a
// 64-reg arch-VGPR budget (128 split VGPR/AGPR) and the ~90-reg loop spilled
// ~60MB/dispatch of scratch (WRITE_SIZE 77MB vs 17MB real outputs).
__global__ __launch_bounds__(512, 2) void vq_main(const float* __restrict__ z,
                                                  const float* __restrict__ cb,
                                                  const float* __restrict__ cc,
                                                  const unsigned short* __restrict__ cbh,
                                                  const unsigned short* __restrict__ cbm,
                                                  float* __restrict__ out) {
    const int t    = threadIdx.x;
    const int lane = t & 63;
    const int wid  = t >> 6;
    const int rowbase = blockIdx.x * 128;

    __shared__ float s_zs[128 * 68];   // z tile fp32, stride 68 (34816 B)
    __shared__ float s_cc[1024];       // ||c||^2 (4096 B)
    __shared__ int   s_final[128];
    __shared__ float s_rd[512];        // rescore dists; aliased as SSE reduce
    __shared__ int   s_ri[512];
    __shared__ int   s_flag[128];
    __shared__ int   s_nflag;

    if (t == 0) s_nflag = 0;
    s_cc[t]       = cc[t];
    s_cc[t + 512] = cc[t + 512];

    // Stage z tile: 128 rows x 16 float4 = 2048 float4s; 4 per thread.
    const float4* zb4 = reinterpret_cast<const float4*>(z) + (size_t)blockIdx.x * 2048;
    #pragma unroll
    for (int j = 0; j < 4; ++j) {
        const int f = t + 512 * j;
        const float4 v = zb4[f];
        *reinterpret_cast<float4*>(&s_zs[(f >> 4) * 68 + (f & 15) * 4]) = v;
    }
    __syncthreads();

    // --- build A fragments (hi/mid) for this wave's 16 rows, K=64 ---
    bf16x8 a0h, a0m, a1h, a1m;
    {
        const int ar = wid * 16 + (lane & 15);   // A row = lane&15
        const int kb = (lane >> 4) * 8;          // k base = 8*(lane>>4)
        #pragma unroll
        for (int e = 0; e < 8; ++e) {
            const float v0 = s_zs[ar * 68 + kb + e];
            const unsigned short h0 = b16(v0);
            a0h[e] = (short)h0;
            a0m[e] = (short)b16(v0 - b2f(h0));
            const float v1 = s_zs[ar * 68 + 32 + kb + e];
            const unsigned short h1 = b16(v1);
            a1h[e] = (short)h1;
            a1m[e] = (short)b16(v1 - b2f(h1));
        }
    }

    // --- sweep all 1024 codes, 16 per step, coalesced + prefetched B ---
    const int lcol = lane & 15;
    const bf16x8* cbh8 = reinterpret_cast<const bf16x8*>(cbh);
    const bf16x8* cbm8 = reinterpret_cast<const bf16x8*>(cbm);

    float bd[4], b2v[4]; int bk[4];
    #pragma unroll
    for (int j = 0; j < 4; ++j) { bd[j] = 3.4e38f; b2v[j] = 3.4e38f; bk[j] = 0; }

    bf16x8 bh0 = cbh8[lane],      bh1 = cbh8[64 + lane];
    bf16x8 bm0 = cbm8[lane],      bm1 = cbm8[64 + lane];
    for (int g = 0; g < 64; ++g) {
        const int nb = ((g + 1) & 63) * 128;     // wrap: last prefetch harmless
        const bf16x8 nh0 = cbh8[nb + lane],      nh1 = cbh8[nb + 64 + lane];
        const bf16x8 nm0 = cbm8[nb + lane],      nm1 = cbm8[nb + 64 + lane];

        f32x4 p0 = {0.f, 0.f, 0.f, 0.f};
        f32x4 p1 = {0.f, 0.f, 0.f, 0.f};
        p0 = __builtin_amdgcn_mfma_f32_16x16x32_bf16(a0m, bh0, p0, 0, 0, 0);
        p1 = __builtin_amdgcn_mfma_f32_16x16x32_bf16(a1m, bh1, p1, 0, 0, 0);
        p0 = __builtin_amdgcn_mfma_f32_16x16x32_bf16(a0h, bm0, p0, 0, 0, 0);
        p1 = __builtin_amdgcn_mfma_f32_16x16x32_bf16(a1h, bm1, p1, 0, 0, 0);
        p0 = __builtin_amdgcn_mfma_f32_16x16x32_bf16(a0h, bh0, p0, 0, 0, 0);
        p1 = __builtin_amdgcn_mfma_f32_16x16x32_bf16(a1h, bh1, p1, 0, 0, 0);

        const float ccv = s_cc[g * 16 + lcol];
        #pragma unroll
        for (int j = 0; j < 4; ++j) {
            const float s = fmaf(-2.f, p0[j] + p1[j], ccv);
            if (s < bd[j]) { b2v[j] = bd[j]; bd[j] = s; bk[j] = g * 16 + lcol; }
            else if (s < b2v[j]) b2v[j] = s;
        }
        bh0 = nh0; bh1 = nh1; bm0 = nm0; bm1 = nm1;
    }

    // --- cross-lane argmin over the 16 code-columns (exact first-index) ---
    #pragma unroll
    for (int m = 1; m < 16; m <<= 1) {
        #pragma unroll
        for (int j = 0; j < 4; ++j) {
            const float od = __shfl_xor(bd[j],  m);
            const int   oi = __shfl_xor(bk[j],  m);
            const float o2 = __shfl_xor(b2v[j], m);
            const float nb2 = fminf(fmaxf(bd[j], od), fminf(b2v[j], o2));
            if (od < bd[j] || (od == bd[j] && oi < bk[j])) { bd[j] = od; bk[j] = oi; }
            b2v[j] = nb2;
        }
    }
    if ((lane & 15) == 0) {
        #pragma unroll
        for (int j = 0; j < 4; ++j) {
            const int r = wid * 16 + ((lane >> 4) << 2) + j;   // D row mapping
            s_final[r] = bk[j];
            if (b2v[j] - bd[j] < MARGIN_W) {
                const int p = atomicAdd(&s_nflag, 1);
                s_flag[p] = r;
            }
        }
    }
    __syncthreads();

    // --- exact fp32 rescore for margin-flagged rows (rare) ---
    const int nf = s_nflag;
    for (int i = 0; i < nf; ++i) {
        const int r = s_flag[i];
        float bestd = 3.4e38f; int besti = 0;
        #pragma unroll
        for (int h = 0; h < 2; ++h) {
            const int code = t + 512 * h;
            const float4* c4 = reinterpret_cast<const float4*>(cb + (size_t)code * 64);
            float ac[4] = {0.f, 0.f, 0.f, 0.f};
            #pragma unroll
            for (int q = 0; q < 16; ++q) {
                const float4 zq = *reinterpret_cast<const float4*>(&s_zs[r * 68 + q * 4]);
                const float4 cq = c4[q];
                ac[q & 3] = fmaf(zq.x, cq.x, ac[q & 3]);
                ac[q & 3] = fmaf(zq.y, cq.y, ac[q & 3]);
                ac[q & 3] = fmaf(zq.z, cq.z, ac[q & 3]);
                ac[q & 3] = fmaf(zq.w, cq.w, ac[q & 3]);
            }
            const float d = fmaf(-2.f, (ac[0] + ac[1]) + (ac[2] + ac[3]), s_cc[code]);
            if (d < bestd) { bestd = d; besti = code; }   // h=0 first: low idx on tie
        }
        s_rd[t] = bestd; s_ri[t] = besti;
        __syncthreads();
        for (int off = 256; off > 0; off >>= 1) {
            if (t < off) {
                const float d = s_rd[t + off]; const int ii = s_ri[t + off];
                if (d < s_rd[t] || (d == s_rd[t] && ii < s_ri[t])) {
                    s_rd[t] = d; s_ri[t] = ii;
                }
            }
            __syncthreads();
        }
        if (t == 0) s_final[r] = s_ri[0];
        __syncthreads();
    }

    // --- indices ---
    if (t < 128) {
        out[OFF_IDX + rowbase + t] = (float)s_final[t];
    }

    // --- phase 2: z_q write + commitment SSE (no cluster atomics) ---
    float sse = 0.f;
    float4*       qb  = reinterpret_cast<float4*>(out + OFF_ZQ) + (size_t)blockIdx.x * 2048;
    const float4* cb4 = reinterpret_cast<const float4*>(cb);
    #pragma unroll
    for (int j = 0; j < 4; ++j) {
        const int f  = t + 512 * j;
        const int r  = f >> 4;
        const int fc = f & 15;
        const int gk = s_final[r];
        const float4 zv = *reinterpret_cast<const float4*>(&s_zs[r * 68 + fc * 4]);
        const float4 cv = cb4[gk * 16 + fc];
        qb[f] = cv;                      // z_q_st == z_q numerically
        const float e0 = zv.x - cv.x, e1 = zv.y - cv.y;
        const float e2 = zv.z - cv.z, e3 = zv.w - cv.w;
        sse += e0 * e0 + e1 * e1 + e2 * e2 + e3 * e3;
    }

    float* s_red = s_rd;                 // reuse rescore buffer for SSE reduce
    s_red[t] = sse;
    __syncthreads();
    for (int off = 256; off > 0; off >>= 1) {
        if (t < off) s_red[t] += s_red[t + off];
        __syncthreads();
    }
    if (t == 0) atomicAdd(&out[OFF_LOSS], s_red[0]);
}

// 1024 blocks x 512 threads (8 waves). Block owns ONE code; wave w scans row
// stripe [w*8192, (w+1)*8192) in 128 coalesced 64-row idx loads (1-deep
// software pipeline). Round-12 finding: 512-block version was latency-bound
// at 8 waves/CU (Occupancy 10%, VALUBusy 6.6%); this runs 32 waves/CU with
// half the per-wave ballot work. ZERO global atomics, deterministic
// ascending-row summation.
__global__ __launch_bounds__(512) void vq_sums(const float* __restrict__ z,
                                               float* __restrict__ out,
                                               float* __restrict__ cnt) {
    const int t    = threadIdx.x;
    const int lane = t & 63;
    const int w    = t >> 6;
    const int k    = blockIdx.x;
    const int base = w * 8192;

    float acc = 0.f;
    int   c   = 0;

    int cur = (int)out[OFF_IDX + base + lane];
    for (int r0 = 0; r0 < 8192; r0 += 64) {
        int nxt = 0;
        if (r0 + 64 < 8192) nxt = (int)out[OFF_IDX + base + r0 + 64 + lane];
        c += (cur == k);
        unsigned long long m = __ballot(cur == k);
        while (m) {
            const int j = __ffsll((long long)m) - 1; m &= m - 1;
            acc += z[(size_t)(base + r0 + j) * 64 + lane];
        }
        cur = nxt;
    }

    // cross-lane count reduce
    #pragma unroll
    for (int m2 = 32; m2 >= 1; m2 >>= 1) c += __shfl_xor(c, m2);

    __shared__ float s_a[8][64];
    __shared__ int   s_c[8];
    if (lane == 0) s_c[w] = c;
    s_a[w][lane] = acc;
    __syncthreads();
    if (w == 0) {
        float s = s_a[0][lane];
        #pragma unroll
        for (int i = 1; i < 8; ++i) s += s_a[i][lane];
        out[OFF_NEW + k * 64 + lane] = s;
        if (lane == 0) {
            int ct = s_c[0];
            #pragma unroll
            for (int i = 1; i < 8; ++i) ct += s_c[i];
            cnt[k] = (float)ct;
        }
    }
}

// 64 blocks x 1024 threads: merged finalize. Every block redundantly computes
// necs + n + den for all 1024 codes; block b writes its 16-code slice of
// new_ecs and its 1024-element slice of new_ew/new_cb.
__global__ __launch_bounds__(1024) void vq_final(const float* __restrict__ ema_cs,
                                                 const float* __restrict__ ema_w,
                                                 const float* __restrict__ cnt,
                                                 float* __restrict__ out) {
    const int k = threadIdx.x;           // code 0..1023
    const int b = blockIdx.x;
    const float necs = DECAY * ema_cs[k] + ONEM * cnt[k];

    __shared__ float s_red[1024];
    __shared__ float s_den[1024];
    s_red[k] = necs;
    __syncthreads();
    for (int off = 512; off > 0; off >>= 1) {
        if (k < off) s_red[k] += s_red[k + off];
        __syncthreads();
    }
    const float n = s_red[0];
    s_den[k] = (necs + EPSV) / (n + (float)KC * EPSV) * n;
    if (k >= b * 16 && k < (b + 1) * 16) out[OFF_NECS + k] = necs;
    __syncthreads();

    const int e = b * 1024 + k;          // this block's slice, coalesced
    const float s  = out[OFF_NEW + e];   // raw cluster sum
    const float ew = DECAY * ema_w[e] + ONEM * s;
    out[OFF_NEW + e] = ew;               // new_ew
    out[OFF_NCB + e] = ew / s_den[e >> 6];  // new_codebook
    if (b == 0 && k == 0) out[OFF_LOSS] = 0.25f * out[OFF_LOSS] * (1.f / 4194304.f);
}

extern "C" void kernel_launch(void* const* d_in, const int* in_sizes, int n_in,
                              void* d_out, int out_size, void* d_ws, size_t ws_size,
                              hipStream_t stream) {
    const float* z   = (const float*)d_in[0];
    const float* cb  = (const float*)d_in[1];
    const float* ecs = (const float*)d_in[2];
    const float* ew  = (const float*)d_in[3];
    float* out = (float*)d_out;

    unsigned short* cbh = (unsigned short*)d_ws;
    unsigned short* cbm = (unsigned short*)((char*)d_ws + 131072);
    float*          cnt = (float*)((char*)d_ws + 262144);

    vq_prep <<<256,  256, 0, stream>>>(cb, out, cbh, cbm);
    vq_main <<<512,  512, 0, stream>>>(z, cb, out + OFF_NCB, cbh, cbm, out);
    vq_sums <<<1024, 512, 0, stream>>>(z, out, cnt);
    vq_final<<<64,  1024, 0, stream>>>(ecs, ew, cnt, out);
}

// Round 14
// 133.303 us; speedup vs baseline: 2.5977x; 1.2524x over previous
//
#include <hip/hip_runtime.h>

// Problem constants
#define KC   1024        // codebook size
#define DD   64          // code dim
#define NR   65536       // total rows (16*4096)

#define DECAY     0.99f
#define ONEM      0.01f
#define EPSV      1e-5f
#define MARGIN_W  0.008f  // rescore window: >= 2x worst split-bf16 error (~2e-3)

// d_out layout (floats), in reference return order:
#define OFF_ZQ    0
#define OFF_LOSS  4194304
#define OFF_IDX   4194305
#define OFF_NCB   4259841
#define OFF_NECS  4325377
#define OFF_NEW   4326401

// Scratch aliases inside d_out:
//   SSE -> OFF_LOSS (zeroed by prep); ||c||^2 table -> first 1024 of OFF_NCB.
//   OFF_NEW raw sums fully WRITTEN by vq_sums (no atomics, no zeroing).
// d_ws layout (bytes): [0,131072) cbh bf16 (fragment-permuted),
//   [131072,262144) cbm bf16 (fragment-permuted), [262144,266240) cnt (1024 f32),
//   [266240,528384) cbT fp32 transposed codebook [d][code] (rescore reads).

typedef float  f32x4  __attribute__((ext_vector_type(4)));
typedef short  bf16x8 __attribute__((ext_vector_type(8)));

__device__ __forceinline__ unsigned short b16(float v) {
    union { float f; unsigned u; } x; x.f = v;
    return (unsigned short)((x.u + 0x7fffu + ((x.u >> 16) & 1u)) >> 16);
}
__device__ __forceinline__ float b2f(unsigned short h) {
    union { unsigned u; float f; } x; x.u = (unsigned)h << 16;
    return x.f;
}

// 256 blocks x 256 threads: ||c||^2 table, fragment-permuted hi/mid splits,
// and the fp32 transposed codebook cbT[d][code].
__global__ void vq_prep(const float* __restrict__ cb, float* __restrict__ out,
                        unsigned short* __restrict__ cbh,
                        unsigned short* __restrict__ cbm,
                        float* __restrict__ cbT) {
    const int tid = blockIdx.x * blockDim.x + threadIdx.x;
    if (tid < 65536) {
        const int code = tid >> 6, d = tid & 63;
        const int g   = code >> 4, col = code & 15;
        const int kh  = d >> 5, hi2 = (d >> 3) & 3, e = d & 7;
        const int pi  = ((g * 2 + kh) * 64 + hi2 * 16 + col) * 8 + e;
        const float v = cb[tid];
        const unsigned short h = b16(v);
        cbh[pi] = h;
        cbm[pi] = b16(v - b2f(h));
        cbT[d * 1024 + code] = v;                // transposed fp32 copy
    }
    if (tid < 1024) {
        const float4* c = reinterpret_cast<const float4*>(cb + tid * 64);
        float s = 0.f;
        #pragma unroll
        for (int j = 0; j < 16; ++j) {
            const float4 v = c[j];
            s += v.x*v.x + v.y*v.y + v.z*v.z + v.w*v.w;
        }
        out[OFF_NCB + tid] = s;                  // ||c_k||^2 (fp32)
    }
    if (tid == 0) out[OFF_LOSS] = 0.0f;          // SSE accumulator
}

// 512 blocks x 512 threads (8 waves). Block owns 128 rows; wave owns 16 rows
// and sweeps ALL 1024 codes with mfma_f32_16x16x32_bf16, split-bf16 3-pass.
// Rescore (round-13 fix): margin-flagged rows are re-scored COOPERATIVELY --
// each wave owns a 128-code slice (2 codes/lane, coalesced cbT reads, 256KB
// read once per block), candidates merged via an 8x128 LDS table. Replaces
// the block-serial per-row rescore whose ~10 barriers/row dominated runtime.
__global__ __launch_bounds__(512, 2) void vq_main(const float* __restrict__ z,
                                                  const float* __restrict__ cc,
                                                  const unsigned short* __restrict__ cbh,
                                                  const unsigned short* __restrict__ cbm,
                                                  const float* __restrict__ cbT,
                                                  const float* __restrict__ cb,
                                                  float* __restrict__ out) {
    const int t    = threadIdx.x;
    const int lane = t & 63;
    const int wid  = t >> 6;
    const int rowbase = blockIdx.x * 128;

    __shared__ float s_zs[128 * 68];   // z tile fp32, stride 68 (34816 B)
    __shared__ float s_cc[1024];       // ||c||^2 (4096 B)
    __shared__ int   s_final[128];
    __shared__ float s_red[512];       // SSE reduce
    __shared__ int   s_flag[128];
    __shared__ float s_cd[8][128];     // rescore candidate dist per wave
    __shared__ int   s_cix[8][128];    // rescore candidate idx per wave
    __shared__ int   s_nflag;

    if (t == 0) s_nflag = 0;
    s_cc[t]       = cc[t];
    s_cc[t + 512] = cc[t + 512];

    // Stage z tile: 128 rows x 16 float4 = 2048 float4s; 4 per thread.
    const float4* zb4 = reinterpret_cast<const float4*>(z) + (size_t)blockIdx.x * 2048;
    #pragma unroll
    for (int j = 0; j < 4; ++j) {
        const int f = t + 512 * j;
        const float4 v = zb4[f];
        *reinterpret_cast<float4*>(&s_zs[(f >> 4) * 68 + (f & 15) * 4]) = v;
    }
    __syncthreads();

    // --- build A fragments (hi/mid) for this wave's 16 rows, K=64 ---
    bf16x8 a0h, a0m, a1h, a1m;
    {
        const int ar = wid * 16 + (lane & 15);   // A row = lane&15
        const int kb = (lane >> 4) * 8;          // k base = 8*(lane>>4)
        #pragma unroll
        for (int e = 0; e < 8; ++e) {
            const float v0 = s_zs[ar * 68 + kb + e];
            const unsigned short h0 = b16(v0);
            a0h[e] = (short)h0;
            a0m[e] = (short)b16(v0 - b2f(h0));
            const float v1 = s_zs[ar * 68 + 32 + kb + e];
            const unsigned short h1 = b16(v1);
            a1h[e] = (short)h1;
            a1m[e] = (short)b16(v1 - b2f(h1));
        }
    }

    // --- sweep all 1024 codes, 16 per step, coalesced + prefetched B ---
    const int lcol = lane & 15;
    const bf16x8* cbh8 = reinterpret_cast<const bf16x8*>(cbh);
    const bf16x8* cbm8 = reinterpret_cast<const bf16x8*>(cbm);

    float bd[4], b2v[4]; int bk[4];
    #pragma unroll
    for (int j = 0; j < 4; ++j) { bd[j] = 3.4e38f; b2v[j] = 3.4e38f; bk[j] = 0; }

    bf16x8 bh0 = cbh8[lane],      bh1 = cbh8[64 + lane];
    bf16x8 bm0 = cbm8[lane],      bm1 = cbm8[64 + lane];
    for (int g = 0; g < 64; ++g) {
        const int nb = ((g + 1) & 63) * 128;     // wrap: last prefetch harmless
        const bf16x8 nh0 = cbh8[nb + lane],      nh1 = cbh8[nb + 64 + lane];
        const bf16x8 nm0 = cbm8[nb + lane],      nm1 = cbm8[nb + 64 + lane];

        f32x4 p0 = {0.f, 0.f, 0.f, 0.f};
        f32x4 p1 = {0.f, 0.f, 0.f, 0.f};
        p0 = __builtin_amdgcn_mfma_f32_16x16x32_bf16(a0m, bh0, p0, 0, 0, 0);
        p1 = __builtin_amdgcn_mfma_f32_16x16x32_bf16(a1m, bh1, p1, 0, 0, 0);
        p0 = __builtin_amdgcn_mfma_f32_16x16x32_bf16(a0h, bm0, p0, 0, 0, 0);
        p1 = __builtin_amdgcn_mfma_f32_16x16x32_bf16(a1h, bm1, p1, 0, 0, 0);
        p0 = __builtin_amdgcn_mfma_f32_16x16x32_bf16(a0h, bh0, p0, 0, 0, 0);
        p1 = __builtin_amdgcn_mfma_f32_16x16x32_bf16(a1h, bh1, p1, 0, 0, 0);

        const float ccv = s_cc[g * 16 + lcol];
        #pragma unroll
        for (int j = 0; j < 4; ++j) {
            const float s = fmaf(-2.f, p0[j] + p1[j], ccv);
            if (s < bd[j]) { b2v[j] = bd[j]; bd[j] = s; bk[j] = g * 16 + lcol; }
            else if (s < b2v[j]) b2v[j] = s;
        }
        bh0 = nh0; bh1 = nh1; bm0 = nm0; bm1 = nm1;
    }

    // --- cross-lane argmin over the 16 code-columns (exact first-index) ---
    #pragma unroll
    for (int m = 1; m < 16; m <<= 1) {
        #pragma unroll
        for (int j = 0; j < 4; ++j) {
            const float od = __shfl_xor(bd[j],  m);
            const int   oi = __shfl_xor(bk[j],  m);
            const float o2 = __shfl_xor(b2v[j], m);
            const float nb2 = fminf(fmaxf(bd[j], od), fminf(b2v[j], o2));
            if (od < bd[j] || (od == bd[j] && oi < bk[j])) { bd[j] = od; bk[j] = oi; }
            b2v[j] = nb2;
        }
    }
    if ((lane & 15) == 0) {
        #pragma unroll
        for (int j = 0; j < 4; ++j) {
            const int r = wid * 16 + ((lane >> 4) << 2) + j;   // D row mapping
            s_final[r] = bk[j];
            if (b2v[j] - bd[j] < MARGIN_W) {
                const int p = atomicAdd(&s_nflag, 1);
                s_flag[p] = r;
            }
        }
    }
    __syncthreads();

    // --- cooperative exact fp32 rescore: wave owns codes [wid*128, +128) ---
    const int nf = s_nflag;
    if (nf > 0) {
        const int cbase = wid * 128;
        const int c0i = cbase + lane, c1i = c0i + 64;
        for (int i = 0; i < nf; ++i) {
            const int r = s_flag[i];
            float a0 = 0.f, a1 = 0.f;
            #pragma unroll 8
            for (int d = 0; d < 64; ++d) {
                const float zd = s_zs[r * 68 + d];         // LDS broadcast
                const float* cr = cbT + d * 1024 + cbase + lane;  // coalesced
                a0 = fmaf(zd, cr[0],  a0);
                a1 = fmaf(zd, cr[64], a1);
            }
            float bd_ = fmaf(-2.f, a0, s_cc[c0i]); int bi_ = c0i;
            const float d1 = fmaf(-2.f, a1, s_cc[c1i]);
            if (d1 < bd_) { bd_ = d1; bi_ = c1i; }         // c0i < c1i
            #pragma unroll
            for (int m = 32; m >= 1; m >>= 1) {
                const float od = __shfl_xor(bd_, m);
                const int   oi = __shfl_xor(bi_, m);
                if (od < bd_ || (od == bd_ && oi < bi_)) { bd_ = od; bi_ = oi; }
            }
            if (lane == 0) { s_cd[wid][i] = bd_; s_cix[wid][i] = bi_; }
        }
    }
    __syncthreads();
    if (t < nf) {                         // finalize: lex-min over 8 waves
        float bd_ = s_cd[0][t]; int bi_ = s_cix[0][t];
        #pragma unroll
        for (int w = 1; w < 8; ++w) {
            const float d = s_cd[w][t]; const int i2 = s_cix[w][t];
            if (d < bd_ || (d == bd_ && i2 < bi_)) { bd_ = d; bi_ = i2; }
        }
        s_final[s_flag[t]] = bi_;
    }
    __syncthreads();

    // --- indices ---
    if (t < 128) {
        out[OFF_IDX + rowbase + t] = (float)s_final[t];
    }

    // --- phase 2: z_q write + commitment SSE (no cluster atomics) ---
    float sse = 0.f;
    float4*       qb  = reinterpret_cast<float4*>(out + OFF_ZQ) + (size_t)blockIdx.x * 2048;
    const float4* cb4 = reinterpret_cast<const float4*>(cb);
    #pragma unroll
    for (int j = 0; j < 4; ++j) {
        const int f  = t + 512 * j;
        const int r  = f >> 4;
        const int fc = f & 15;
        const int gk = s_final[r];
        const float4 zv = *reinterpret_cast<const float4*>(&s_zs[r * 68 + fc * 4]);
        const float4 cv = cb4[gk * 16 + fc];
        qb[f] = cv;                      // z_q_st == z_q numerically
        const float e0 = zv.x - cv.x, e1 = zv.y - cv.y;
        const float e2 = zv.z - cv.z, e3 = zv.w - cv.w;
        sse += e0 * e0 + e1 * e1 + e2 * e2 + e3 * e3;
    }

    s_red[t] = sse;
    __syncthreads();
    for (int off = 256; off > 0; off >>= 1) {
        if (t < off) s_red[t] += s_red[t + off];
        __syncthreads();
    }
    if (t == 0) atomicAdd(&out[OFF_LOSS], s_red[0]);
}

// 1024 blocks x 512 threads (8 waves). Block owns ONE code; wave w scans row
// stripe [w*8192, (w+1)*8192) in coalesced 64-row idx loads (1-deep pipeline).
// ZERO global atomics, deterministic ascending-row summation.
__global__ __launch_bounds__(512) void vq_sums(const float* __restrict__ z,
                                               float* __restrict__ out,
                                               float* __restrict__ cnt) {
    const int t    = threadIdx.x;
    const int lane = t & 63;
    const int w    = t >> 6;
    const int k    = blockIdx.x;
    const int base = w * 8192;

    float acc = 0.f;
    int   c   = 0;

    int cur = (int)out[OFF_IDX + base + lane];
    for (int r0 = 0; r0 < 8192; r0 += 64) {
        int nxt = 0;
        if (r0 + 64 < 8192) nxt = (int)out[OFF_IDX + base + r0 + 64 + lane];
        c += (cur == k);
        unsigned long long m = __ballot(cur == k);
        while (m) {
            const int j = __ffsll((long long)m) - 1; m &= m - 1;
            acc += z[(size_t)(base + r0 + j) * 64 + lane];
        }
        cur = nxt;
    }

    // cross-lane count reduce
    #pragma unroll
    for (int m2 = 32; m2 >= 1; m2 >>= 1) c += __shfl_xor(c, m2);

    __shared__ float s_a[8][64];
    __shared__ int   s_c[8];
    if (lane == 0) s_c[w] = c;
    s_a[w][lane] = acc;
    __syncthreads();
    if (w == 0) {
        float s = s_a[0][lane];
        #pragma unroll
        for (int i = 1; i < 8; ++i) s += s_a[i][lane];
        out[OFF_NEW + k * 64 + lane] = s;
        if (lane == 0) {
            int ct = s_c[0];
            #pragma unroll
            for (int i = 1; i < 8; ++i) ct += s_c[i];
            cnt[k] = (float)ct;
        }
    }
}

// 64 blocks x 1024 threads: merged finalize. Every block redundantly computes
// necs + n + den for all 1024 codes; block b writes its 16-code slice of
// new_ecs and its 1024-element slice of new_ew/new_cb.
__global__ __launch_bounds__(1024) void vq_final(const float* __restrict__ ema_cs,
                                                 const float* __restrict__ ema_w,
                                                 const float* __restrict__ cnt,
                                                 float* __restrict__ out) {
    const int k = threadIdx.x;           // code 0..1023
    const int b = blockIdx.x;
    const float necs = DECAY * ema_cs[k] + ONEM * cnt[k];

    __shared__ float s_red[1024];
    __shared__ float s_den[1024];
    s_red[k] = necs;
    __syncthreads();
    for (int off = 512; off > 0; off >>= 1) {
        if (k < off) s_red[k] += s_red[k + off];
        __syncthreads();
    }
    const float n = s_red[0];
    s_den[k] = (necs + EPSV) / (n + (float)KC * EPSV) * n;
    if (k >= b * 16 && k < (b + 1) * 16) out[OFF_NECS + k] = necs;
    __syncthreads();

    const int e = b * 1024 + k;          // this block's slice, coalesced
    const float s  = out[OFF_NEW + e];   // raw cluster sum
    const float ew = DECAY * ema_w[e] + ONEM * s;
    out[OFF_NEW + e] = ew;               // new_ew
    out[OFF_NCB + e] = ew / s_den[e >> 6];  // new_codebook
    if (b == 0 && k == 0) out[OFF_LOSS] = 0.25f * out[OFF_LOSS] * (1.f / 4194304.f);
}

extern "C" void kernel_launch(void* const* d_in, const int* in_sizes, int n_in,
                              void* d_out, int out_size, void* d_ws, size_t ws_size,
                              hipStream_t stream) {
    const float* z   = (const float*)d_in[0];
    const float* cb  = (const float*)d_in[1];
    const float* ecs = (const float*)d_in[2];
    const float* ew  = (const float*)d_in[3];
    float* out = (float*)d_out;

    unsigned short* cbh = (unsigned short*)d_ws;
    unsigned short* cbm = (unsigned short*)((char*)d_ws + 131072);
    float*          cnt = (float*)((char*)d_ws + 262144);
    float*          cbT = (float*)((char*)d_ws + 266240);

    vq_prep <<<256,  256, 0, stream>>>(cb, out, cbh, cbm, cbT);
    vq_main <<<512,  512, 0, stream>>>(z, out + OFF_NCB, cbh, cbm, cbT, cb, out);
    vq_sums <<<1024, 512, 0, stream>>>(z, out, cnt);
    vq_final<<<64,  1024, 0, stream>>>(ecs, ew, cnt, out);
}